// Round 6
// baseline (153.824 us; speedup 1.0000x reference)
//
#include <hip/hip_runtime.h>
#include <math.h>

#define L2C  1e-4
#define SIGC 0.1
#define NITER 20
#define WPB  8   // waves (batch elements) per block: 8 waves -> 2 per SIMD

// permlane swaps via builtins (R2-proven green; R0/R1 asm variants NaN'd:
// regalloc coalescing + unhandled VALU->permlane hazard inside asm blobs).
#if defined(__has_builtin)
#  if __has_builtin(__builtin_amdgcn_permlane16_swap) && __has_builtin(__builtin_amdgcn_permlane32_swap)
#    define HAVE_PLSWAP 1
#  endif
#  if __has_builtin(__builtin_amdgcn_rcp)
#    define HAVE_RCP64 1
#  endif
#endif
#ifndef HAVE_PLSWAP
#  define HAVE_PLSWAP 0
#endif
#ifndef HAVE_RCP64
#  define HAVE_RCP64 0
#endif

// ---- cross-lane helpers ----------------------------------------------------
__device__ __forceinline__ double rld(double v, int lane) {
    union { double d; int i[2]; } u, r; u.d = v;
    r.i[0] = __builtin_amdgcn_readlane(u.i[0], lane);
    r.i[1] = __builtin_amdgcn_readlane(u.i[1], lane);
    return r.d;
}
template <int CTRL>
__device__ __forceinline__ double dppd(double v) {
    union { double d; int i[2]; } u, r; u.d = v;
    r.i[0] = __builtin_amdgcn_update_dpp(0, u.i[0], CTRL, 0xF, 0xF, true);
    r.i[1] = __builtin_amdgcn_update_dpp(0, u.i[1], CTRL, 0xF, 0xF, true);
    return r.d;
}
// sum across each 16-lane DPP row (all lanes get the row total)
__device__ __forceinline__ double sum16d(double v) {
    v += dppd<0xB1>(v); v += dppd<0x4E>(v); v += dppd<0x124>(v); v += dppd<0x128>(v);
    return v;
}
template <int CTRL>
__device__ __forceinline__ float dppf(float v) {
    return __int_as_float(__builtin_amdgcn_update_dpp(0, __float_as_int(v), CTRL, 0xF, 0xF, true));
}
__device__ __forceinline__ float min16f(float v) {
    v = fminf(v, dppf<0xB1>(v)); v = fminf(v, dppf<0x4E>(v));
    v = fminf(v, dppf<0x124>(v)); v = fminf(v, dppf<0x128>(v));
    return v;
}
__device__ __forceinline__ double mkd(unsigned lo, unsigned hi) {
    union { unsigned u[2]; double d; } r; r.u[0] = lo; r.u[1] = hi; return r.d;
}
__device__ __forceinline__ void dsplit(double v, unsigned &lo, unsigned &hi) {
    union { double d; unsigned u[2]; } x; x.d = v; lo = x.u[0]; hi = x.u[1];
}
// combine the 4 16-lane rows (sum over {q, q+16, q+32, q+48}); order-independent.
__device__ __forceinline__ double cross4d(double v) {
#if HAVE_PLSWAP
    unsigned lo, hi; dsplit(v, lo, hi);
    auto rl = __builtin_amdgcn_permlane16_swap(lo, lo, false, false);
    auto rh = __builtin_amdgcn_permlane16_swap(hi, hi, false, false);
    v = mkd(rl[0], rh[0]) + mkd(rl[1], rh[1]);
    dsplit(v, lo, hi);
    auto sl = __builtin_amdgcn_permlane32_swap(lo, lo, false, false);
    auto sh = __builtin_amdgcn_permlane32_swap(hi, hi, false, false);
    return mkd(sl[0], sh[0]) + mkd(sl[1], sh[1]);
#else
    v += __shfl_xor(v, 16, 64); v += __shfl_xor(v, 32, 64); return v;
#endif
}
__device__ __forceinline__ float cross4minf(float v) {
#if HAVE_PLSWAP
    auto a = __builtin_amdgcn_permlane16_swap(__float_as_uint(v), __float_as_uint(v), false, false);
    v = fminf(__uint_as_float(a[0]), __uint_as_float(a[1]));
    auto b = __builtin_amdgcn_permlane32_swap(__float_as_uint(v), __float_as_uint(v), false, false);
    return fminf(__uint_as_float(b[0]), __uint_as_float(b[1]));
#else
    v = fminf(v, __shfl_xor(v, 16, 64)); v = fminf(v, __shfl_xor(v, 32, 64)); return v;
#endif
}
// fast fp64 reciprocal (v_rcp_f64 seed + one Newton), ~1e-14 rel err.
__device__ __forceinline__ double drcp(double d) {
#if HAVE_RCP64
    double x = __builtin_amdgcn_rcp(d);
#else
    double x = (double)__builtin_amdgcn_rcpf((float)d);
#endif
    x = x * (2.0 - d * x);
    return x;
}
__device__ __forceinline__ float frcpf(float x) { return __builtin_amdgcn_rcpf(x); }

// One 64-lane wave per batch element; lane l: q=l&15, r=l>>4; owns cells
// (q, 4c+r). fp64 state, sigma=0.1, separate primal/dual steps, exit at
// mu<1e-4 (harness-proven numerics; R4 structure unchanged).
// R5: OCCUPANCY. fp64 is half-rate (wave64 v_*_f64 occupies the SIMD-32
// ~4cy) -> one wave alone demands ~60-65% of its SIMD's issue-occupancy;
// chain-trimming rounds (R2-R4) returned only 1-3% because stalls hide
// under fp64 occupancy AND nothing fills the rest. Previously: 32 blocks x
// 1 wave = 1 wave/SIMD, 224 CUs idle. Now: 8 independent waves (8 batch
// elements) per 512-thread block -> 2 waves/SIMD co-resident; the SIMD
// interleaves them per-cycle, filling each wave's stalls with the other's
// issue. No barriers; per-wave private LDS slices. Sst/Lst are time-
// disjoint (S consumed into regs before first L write) -> overlaid in SLst:
// 4608 B/wave, 36.9 KB/block.
__global__ __launch_bounds__(64 * WPB, 2) void emd_ip_kernel(const float* __restrict__ jets1,
                                                             const float* __restrict__ jets2,
                                                             float* __restrict__ out,
                                                             int Btot) {
    const int l = threadIdx.x & 63;        // lane within wave
    const int w = threadIdx.x >> 6;        // wave within block
    const int b = blockIdx.x * WPB + w;    // batch element
    const int q = l & 15;
    const int r = l >> 4;

    __shared__ double invDl_s[WPB][16 * 17];   // C[i][j] at i*17+j (stride-17)
    __shared__ double SLst_s[WPB][16 * 17];    // Schur staging (fallback) OVERLAID with L columns
    __shared__ double Gst_s[WPB][2][16];       // rhs staging: [0]=R, [1]=I

    if (b >= Btot) return;
    double* invDl = invDl_s[w];
    double* SLst  = SLst_s[w];
    double (*Gst)[16] = Gst_s[w];

    const float* p1 = jets1 + b * 48;
    const float* p2 = jets2 + b * 48;

    double ax = (double)p1[3 * q], ay = (double)p1[3 * q + 1];
    double px[4];
#pragma unroll
    for (int c = 0; c < 4; c++) {
        int j = 4 * c + r;
        double d0 = ((double)p2[3 * j]     - ax) + 1e-12;
        double d1 = ((double)p2[3 * j + 1] - ay) + 1e-12;
        px[c] = sqrt(d0 * d0 + d1 * d1);
    }
    double h_rt = (double)p1[3 * q + 2];
    double h_ct[4];
#pragma unroll
    for (int c = 0; c < 4; c++) h_ct[c] = (double)p2[3 * (4 * c + r) + 2];

    double sw1 = sum16d(h_rt);
    double sw2 = sum16d((double)p2[3 * q + 2]);
    const double sB = fmin(sw1, sw2);
    const double sE = fabs(sw1 - sw2);

    // probe the permlane-swap output convention once (ISA-derived expectation:
    // ret0 = x[l&~m], ret1 = x[l|m]); fallback to LDS gather if it ever flips.
#if HAVE_PLSWAP
    auto pr16 = __builtin_amdgcn_permlane16_swap((unsigned)l, (unsigned)l, false, false);
    auto pr32 = __builtin_amdgcn_permlane32_swap((unsigned)l, (unsigned)l, false, false);
    const bool convOK = (__builtin_amdgcn_readfirstlane((int)pr16[0]) == 0) &&
                        (__builtin_amdgcn_readfirstlane((int)pr16[1]) == 16) &&
                        (__builtin_amdgcn_readfirstlane((int)pr32[0]) == 0) &&
                        (__builtin_amdgcn_readfirstlane((int)pr32[1]) == 32);
#else
    const bool convOK = false;
#endif

    double x[4] = {0, 0, 0, 0}, s[4] = {1, 1, 1, 1}, z[4] = {1, 1, 1, 1};
    double yv = 0.0;
    double s_rt = 1.0, z_rt = 1.0;
    double s_ct[4] = {1, 1, 1, 1}, z_ct[4] = {1, 1, 1, 1};
    // incrementally-maintained sums of x (x starts at 0)
    double rsx = 0.0;                      // row-q sum of x
    double cs[4] = {0, 0, 0, 0};           // col 4c+r sums of x
    double ra = -sB;                       // sum(x) - sB

    for (int it = 0; it < NITER; ++it) {
        // ---- paired reciprocals + invDl stores (mu-independent; overlap the
        //      mu butterfly and bury the invDl lgkm latency) ----
        double prt = s_rt * z_rt;
        double irt = drcp(prt);
        double is_rt = z_rt * irt, iz_rt = s_rt * irt;
        double srz = (s_rt * s_rt) * irt;      // s_rt/z_rt
        double pct[4], is_ct[4], iz_ct[4];
#pragma unroll
        for (int c = 0; c < 4; c++) {
            pct[c] = s_ct[c] * z_ct[c];
            double ict = drcp(pct[c]);
            is_ct[c] = z_ct[c] * ict;
            iz_ct[c] = s_ct[c] * ict;
        }
        double szc[4], is_[4], iD[4];
#pragma unroll
        for (int c = 0; c < 4; c++) {
            szc[c] = s[c] * z[c];
            double tc = fma(L2C, s[c], z[c]);      // L2C*s + z
            double ip = drcp(s[c] * tc);
            is_[c] = tc * ip;                      // 1/s
            iD[c]  = (s[c] * s[c]) * ip;           // 1/(L2C + z/s)
            invDl[q * 17 + 4 * c + r] = iD[c];
        }

        // ---- mu = mean(s*z) over 288 (redundant copies scaled) ----
        double mub = szc[0] + szc[1] + szc[2] + szc[3]
                   + 0.25 * prt
                   + 0.0625 * (pct[0] + pct[1] + pct[2] + pct[3]);
        double mu = sum16d(cross4d(mub)) * (1.0 / 288.0);
        if (!(mu >= 1e-4)) break;   // gap ~ 288*mu ~ 2.9e-2 < 9.6e-2/2; catches NaN
        double sgmu = SIGC * mu;

        // ---- tail residuals (lane-local; rsx/cs maintained incrementally) ----
        double rp_rt = rsx + s_rt - h_rt;
        double rs_rt = prt - sgmu;
        double tt_rt = (z_rt * (rsx - h_rt) + sgmu) * is_rt;
        double rp_ct[4], rs_ct[4], tt_ct[4];
#pragma unroll
        for (int c = 0; c < 4; c++) {
            rp_ct[c] = cs[c] + s_ct[c] - h_ct[c];
            rs_ct[c] = pct[c] - sgmu;
            tt_ct[c] = (z_ct[c] * (cs[c] - h_ct[c]) + sgmu) * is_ct[c];
        }

        // ---- cell residuals ----
        double rp[4], rs[4], r1[4], rD1[4];
#pragma unroll
        for (int c = 0; c < 4; c++) {
            double rx = L2C * x[c] + px[c] + (-z[c] + z_rt + z_ct[c]) + yv;
            rp[c] = s[c] - x[c];
            rs[c] = szc[c] - sgmu;
            double tk = (sgmu - z[c] * x[c]) * is_[c];   // (z*rp - rs)/s
            r1[c] = rx - tk + tt_rt + tt_ct[c];
            rD1[c] = r1[c] * iD[c];
        }

        // ---- sums of invD, rD1 ----
        double rsI = cross4d(iD[0] + iD[1] + iD[2] + iD[3]);
        double rsR = cross4d(rD1[0] + rD1[1] + rD1[2] + rD1[3]);
        double csI[4];
#pragma unroll
        for (int c = 0; c < 4; c++) csI[c] = sum16d(iD[c]);

        double ar = drcp(srz + rsI);   // 1/A_q
        double aR = ar * rsR;
        double aI = ar * rsI;

        // ---- rhs gp[j] = g_c[j] - sum_i aX_i*C[i][j]; gpR fused (linearity
        //      of sum16d: csR - sum(aR*iD) == sum(rD1 - aR*iD)) ----
        double bb[4];
#pragma unroll
        for (int c = 0; c < 4; c++) {
            double gpR = sum16d(rD1[c] - aR * iD[c]);
            double gpI = csI[c] - sum16d(aI * iD[c]);
            bb[c] = s_ct[c] * iz_ct[c] + csI[c];
            if (q == 4 * c + r) { Gst[0][q] = gpR; Gst[1][q] = gpI; }  // stage
        }

        // ---- Schur S[q][4c+r] = diag - sum_t ar_t C[t][q] C[t][4c+r] ----
        // split accumulators: fp64 fma chain depth 16 -> 8 (+1 add)
        double accA[4] = {0, 0, 0, 0}, accB[4] = {0, 0, 0, 0};
#pragma unroll
        for (int t = 0; t < 8; t++) {
            double wA = rld(ar, t) * invDl[t * 17 + q];
            double wB = rld(ar, t + 8) * invDl[(t + 8) * 17 + q];
#pragma unroll
            for (int c = 0; c < 4; c++) {
                accA[c] += wA * invDl[t * 17 + 4 * c + r];
                accB[c] += wB * invDl[(t + 8) * 17 + 4 * c + r];
            }
        }
        double Sv[4];
#pragma unroll
        for (int c = 0; c < 4; c++)
            Sv[c] = ((q == 4 * c + r) ? bb[c] : 0.0) - (accA[c] + accB[c]);

        // ---- gather row q of S into registers ----
        // fast path: permlane butterfly resolves both r-bits to compile-time
        // slots (~40 VALU b32 swaps, no LDS round trip on the spine).
        double Sr[16];
#if HAVE_PLSWAP
        if (convOK) {
#pragma unroll
            for (int c = 0; c < 4; c++) {
                unsigned xl, xh; dsplit(Sv[c], xl, xh);
                auto sl = __builtin_amdgcn_permlane16_swap(xl, xl, false, false);
                auto sh = __builtin_amdgcn_permlane16_swap(xh, xh, false, false);
                auto e = __builtin_amdgcn_permlane32_swap(sl[0], sl[0], false, false);
                auto f = __builtin_amdgcn_permlane32_swap(sh[0], sh[0], false, false);
                auto g = __builtin_amdgcn_permlane32_swap(sl[1], sl[1], false, false);
                auto h = __builtin_amdgcn_permlane32_swap(sh[1], sh[1], false, false);
                Sr[4 * c + 0] = mkd(e[0], f[0]);
                Sr[4 * c + 2] = mkd(e[1], f[1]);
                Sr[4 * c + 1] = mkd(g[0], h[0]);
                Sr[4 * c + 3] = mkd(g[1], h[1]);
            }
        } else
#endif
        {
#pragma unroll
            for (int c = 0; c < 4; c++) SLst[q * 17 + 4 * c + r] = Sv[c];
#pragma unroll
            for (int j2 = 0; j2 < 16; j2++) Sr[j2] = SLst[q * 17 + j2];
        }

        // ---- pivot floors precomputed (off the serial pivot chain) ----
        double flo[16];
#pragma unroll
        for (int kk = 0; kk < 16; kk++)
            flo[kk] = fmax(1e-12 * fabs(rld(Sr[kk], kk)), 1e-280);

        // ---- rhs read: one register per lane; r<2 carries R, r>=2 carries I ----
        double ysol = Gst[r >> 1][q];

        // ---- 16x16 LDLT (unit-diag L) + FUSED forward solve ----
        // (S fully in regs by now -> safe to overwrite SLst with L columns.)
        double invdv = 0.0;   // 1/d_q (own pivot) for the D-divide
        double pcand = 0.0;
#pragma unroll
        for (int kk = 0; kk < 16; kk++) {
            double praw = (kk == 0) ? rld(Sr[0], 0) : rld(pcand, kk);
            double dkk = fmax(praw, flo[kk]);
            double inv = drcp(dkk);
            invdv = (q == kk) ? inv : invdv;
            double Lc = Sr[kk] * inv;      // L[q][kk] (unit diag; valid q>=kk)
            if (l < 16) SLst[kk * 17 + l] = Lc;
            if (kk < 15) pcand = Sr[kk + 1] - Sr[kk] * Lc;   // lane-local next-pivot
            // fused forward solve (split halves, one fma)
            double t1 = rld(ysol, kk);
            double t2 = rld(ysol, kk + 32);
            double tt = (r < 2) ? t1 : t2;
            if (q > kk) ysol -= Lc * tt;
#pragma unroll
            for (int jj = kk + 1; jj < 16; jj++)
                Sr[jj] -= Sr[kk] * rld(Lc, jj);   // -= (L[q][kk]*d)*L[jj][kk]
            Sr[kk] = Lc;
        }

        // ---- D-divide (lane-local) ----
        ysol *= invdv;

        // ---- gather L^T row from LDS (issued before the bwd chain starts) ----
        double LTr[16];
#pragma unroll
        for (int kk = 0; kk < 16; kk++) LTr[kk] = SLst[q * 17 + kk];  // L[kk][q]

        // ---- backward solve L^T qc = v (split halves) ----
#pragma unroll
        for (int kk = 15; kk >= 0; kk--) {
            double t1 = rld(ysol, kk);
            double t2 = rld(ysol, kk + 32);
            double tt = (r < 2) ? t1 : t2;
            if (q < kk) ysol -= LTr[kk] * tt;
        }
        // lanes 0..15: ysol = qcR[q]; lanes 32..47: ysol = qcI[q]

        // ---- gather qc per own columns (sourced from the valid halves) ----
        double qc1c[4], qcvc[4];
#pragma unroll
        for (int c = 0; c < 4; c++) {
            qc1c[c] = __shfl(ysol, 4 * c + r, 64);
            qcvc[c] = __shfl(ysol, 32 + 4 * c + r, 64);
        }

        // ---- qr = ar*(g_r - sum_j C[q][j] qc_j) (cross4 reduction) ----
        double pr1 = iD[0]*qc1c[0] + iD[1]*qc1c[1] + iD[2]*qc1c[2] + iD[3]*qc1c[3];
        double prv = iD[0]*qcvc[0] + iD[1]*qcvc[1] + iD[2]*qcvc[2] + iD[3]*qcvc[3];
        double qr1 = ar * (rsR - cross4d(pr1));
        double qrv = ar * (rsI - cross4d(prv));

        // ---- u = H^{-1} r1, v = H^{-1} 1 ----
        double u[4], v[4];
#pragma unroll
        for (int c = 0; c < 4; c++) {
            u[c] = (r1[c] - qr1 - qc1c[c]) * iD[c];
            v[c] = (1.0  - qrv - qcvc[c]) * iD[c];
        }
        double urow = cross4d(u[0] + u[1] + u[2] + u[3]);
        double vrow = cross4d(v[0] + v[1] + v[2] + v[3]);
        double usum = sum16d(urow);
        double vsum = sum16d(vrow);
        double dy = (ra - usum) * drcp(vsum);

        // ---- dx + sums (rsdx reuses urow/vrow) ----
        double dx[4];
#pragma unroll
        for (int c = 0; c < 4; c++) dx[c] = -u[c] - v[c] * dy;
        double rsdx = -urow - vrow * dy;
        double csdx[4];
#pragma unroll
        for (int c = 0; c < 4; c++) csdx[c] = sum16d(dx[c]);
        double sumdx = -usum - vsum * dy;   // sum over all cells of dx (exact identity)

        // ---- ds, dz; SEPARATE primal/dual ratio tests (fp32, 0.99 margin) ----
        float amP = 1e30f, amD = 1e30f;
        double ds[4], dz[4];
#pragma unroll
        for (int c = 0; c < 4; c++) {
            ds[c] = dx[c] - rp[c];
            dz[c] = -(rs[c] + z[c] * ds[c]) * is_[c];
            if (ds[c] < 0.0) amP = fminf(amP, (float)s[c] * frcpf((float)(-ds[c])));
            if (dz[c] < 0.0) amD = fminf(amD, (float)z[c] * frcpf((float)(-dz[c])));
        }
        double ds_rt = -rp_rt - rsdx;
        double dz_rt = -(rs_rt + z_rt * ds_rt) * is_rt;
        if (ds_rt < 0.0) amP = fminf(amP, (float)s_rt * frcpf((float)(-ds_rt)));
        if (dz_rt < 0.0) amD = fminf(amD, (float)z_rt * frcpf((float)(-dz_rt)));
        double ds_ct[4], dz_ct[4];
#pragma unroll
        for (int c = 0; c < 4; c++) {
            ds_ct[c] = -rp_ct[c] - csdx[c];
            dz_ct[c] = -(rs_ct[c] + z_ct[c] * ds_ct[c]) * is_ct[c];
            if (ds_ct[c] < 0.0) amP = fminf(amP, (float)s_ct[c] * frcpf((float)(-ds_ct[c])));
            if (dz_ct[c] < 0.0) amD = fminf(amD, (float)z_ct[c] * frcpf((float)(-dz_ct[c])));
        }
        float aPf = min16f(cross4minf(amP));
        float aDf = min16f(cross4minf(amD));
        double alphaP = 0.99 * fmin(1.0, (double)aPf);
        double alphaD = 0.99 * fmin(1.0, (double)aDf);
        bool good = ((dy - dy) == 0.0);   // freeze on garbage direction
        alphaP = good ? alphaP : 0.0;
        alphaD = good ? alphaD : 0.0;

        // ---- step (x,s with alphaP; z,y with alphaD; x-sums incremental) ----
#pragma unroll
        for (int c = 0; c < 4; c++) {
            x[c] += alphaP * dx[c];
            s[c] += alphaP * ds[c];
            z[c] += alphaD * dz[c];
            s_ct[c] += alphaP * ds_ct[c];
            z_ct[c] += alphaD * dz_ct[c];
            cs[c] += alphaP * csdx[c];
        }
        yv += alphaD * dy;
        s_rt += alphaP * ds_rt;
        z_rt += alphaD * dz_rt;
        rsx += alphaP * rsdx;
        ra  += alphaP * sumdx;
    }

    // ---- emd = p.x + |sum w1 - sum w2| ----
    double e = sum16d(cross4d(px[0]*x[0] + px[1]*x[1] + px[2]*x[2] + px[3]*x[3]));
    if (l == 0) out[b] = (float)(e + sE);
}

extern "C" void kernel_launch(void* const* d_in, const int* in_sizes, int n_in,
                              void* d_out, int out_size, void* d_ws, size_t ws_size,
                              hipStream_t stream) {
    const float* jets1 = (const float*)d_in[0];
    const float* jets2 = (const float*)d_in[1];
    float* out = (float*)d_out;
    int B = in_sizes[0] / 48;   // 32
    int blocks = (B + WPB - 1) / WPB;
    emd_ip_kernel<<<dim3(blocks), dim3(64 * WPB), 0, stream>>>(jets1, jets2, out, B);
}

// Round 7
// 112.829 us; speedup vs baseline: 1.3633x; 1.3633x over previous
//
#include <hip/hip_runtime.h>
#include <math.h>

#define L2C  1e-4
#define SIGC 0.1
#define NITER 20

// permlane swaps via builtins (R2-proven green; R0/R1 asm variants NaN'd:
// regalloc coalescing + unhandled VALU->permlane hazard inside asm blobs).
#if defined(__has_builtin)
#  if __has_builtin(__builtin_amdgcn_permlane16_swap) && __has_builtin(__builtin_amdgcn_permlane32_swap)
#    define HAVE_PLSWAP 1
#  endif
#  if __has_builtin(__builtin_amdgcn_rcp)
#    define HAVE_RCP64 1
#  endif
#  if __has_builtin(__builtin_amdgcn_mfma_f64_16x16x4f64)
#    define HAVE_MFMA64 1
#  endif
#endif
#ifndef HAVE_PLSWAP
#  define HAVE_PLSWAP 0
#endif
#ifndef HAVE_RCP64
#  define HAVE_RCP64 0
#endif
#ifndef HAVE_MFMA64
#  define HAVE_MFMA64 0
#endif

#if HAVE_MFMA64
typedef double v4d __attribute__((ext_vector_type(4)));
#endif

// ---- cross-lane helpers ----------------------------------------------------
__device__ __forceinline__ double rld(double v, int lane) {
    union { double d; int i[2]; } u, r; u.d = v;
    r.i[0] = __builtin_amdgcn_readlane(u.i[0], lane);
    r.i[1] = __builtin_amdgcn_readlane(u.i[1], lane);
    return r.d;
}
template <int CTRL>
__device__ __forceinline__ double dppd(double v) {
    union { double d; int i[2]; } u, r; u.d = v;
    r.i[0] = __builtin_amdgcn_update_dpp(0, u.i[0], CTRL, 0xF, 0xF, true);
    r.i[1] = __builtin_amdgcn_update_dpp(0, u.i[1], CTRL, 0xF, 0xF, true);
    return r.d;
}
// sum across each 16-lane DPP row (all lanes get the row total)
__device__ __forceinline__ double sum16d(double v) {
    v += dppd<0xB1>(v); v += dppd<0x4E>(v); v += dppd<0x124>(v); v += dppd<0x128>(v);
    return v;
}
template <int CTRL>
__device__ __forceinline__ float dppf(float v) {
    return __int_as_float(__builtin_amdgcn_update_dpp(0, __float_as_int(v), CTRL, 0xF, 0xF, true));
}
__device__ __forceinline__ float min16f(float v) {
    v = fminf(v, dppf<0xB1>(v)); v = fminf(v, dppf<0x4E>(v));
    v = fminf(v, dppf<0x124>(v)); v = fminf(v, dppf<0x128>(v));
    return v;
}
__device__ __forceinline__ double mkd(unsigned lo, unsigned hi) {
    union { unsigned u[2]; double d; } r; r.u[0] = lo; r.u[1] = hi; return r.d;
}
__device__ __forceinline__ void dsplit(double v, unsigned &lo, unsigned &hi) {
    union { double d; unsigned u[2]; } x; x.d = v; lo = x.u[0]; hi = x.u[1];
}
// combine the 4 16-lane rows (sum over {q, q+16, q+32, q+48}); order-independent.
__device__ __forceinline__ double cross4d(double v) {
#if HAVE_PLSWAP
    unsigned lo, hi; dsplit(v, lo, hi);
    auto rl = __builtin_amdgcn_permlane16_swap(lo, lo, false, false);
    auto rh = __builtin_amdgcn_permlane16_swap(hi, hi, false, false);
    v = mkd(rl[0], rh[0]) + mkd(rl[1], rh[1]);
    dsplit(v, lo, hi);
    auto sl = __builtin_amdgcn_permlane32_swap(lo, lo, false, false);
    auto sh = __builtin_amdgcn_permlane32_swap(hi, hi, false, false);
    return mkd(sl[0], sh[0]) + mkd(sl[1], sh[1]);
#else
    v += __shfl_xor(v, 16, 64); v += __shfl_xor(v, 32, 64); return v;
#endif
}
__device__ __forceinline__ float cross4minf(float v) {
#if HAVE_PLSWAP
    auto a = __builtin_amdgcn_permlane16_swap(__float_as_uint(v), __float_as_uint(v), false, false);
    v = fminf(__uint_as_float(a[0]), __uint_as_float(a[1]));
    auto b = __builtin_amdgcn_permlane32_swap(__float_as_uint(v), __float_as_uint(v), false, false);
    return fminf(__uint_as_float(b[0]), __uint_as_float(b[1]));
#else
    v = fminf(v, __shfl_xor(v, 16, 64)); v = fminf(v, __shfl_xor(v, 32, 64)); return v;
#endif
}
// fast fp64 reciprocal (v_rcp_f64 seed + one Newton), ~1e-14 rel err.
__device__ __forceinline__ double drcp(double d) {
#if HAVE_RCP64
    double x = __builtin_amdgcn_rcp(d);
#else
    double x = (double)__builtin_amdgcn_rcpf((float)d);
#endif
    x = x * (2.0 - d * x);
    return x;
}
__device__ __forceinline__ float frcpf(float x) { return __builtin_amdgcn_rcpf(x); }

// One 64-lane wave per batch element; lane l: q=l&15, r=l>>4; owns cells
// (q, 4c+r). fp64 state, sigma=0.1, separate primal/dual steps, exit at
// mu<1e-4 (harness-proven numerics; R4 spine).
// R5 LESSON (measured): packing 8 waves/block (2/SIMD, 4 CUs) REGRESSED
// 62.5->102.7us — co-resident fp64-heavy waves contend, they don't overlap.
// 1 wave/CU (32 blocks x 64) is the proven-fastest geometry. REVERTED.
// R6: the Schur build S' = -C^T diag(ar) C is a 16x16x16 fp64 matmul ->
// v_mfma_f64_16x16x4 x4 replaces 80 ds_read_b64 + 64 FMA + 32 readlanes
// per iter (the largest single issue block, ~900cy, on the spine). A and B
// fragments per lane are the SAME LDS value cell(4ch+r, q) (4 b64 reads
// total); ar staged via 16-double LDS row; diag(bb) added post-gather.
// Fragment-layout assumption is verified ONCE in-kernel (exact-integer
// self-test, __all-reduced); mismatch -> unchanged R4 LDS path (no risk).
__global__ __launch_bounds__(64, 1) void emd_ip_kernel(const float* __restrict__ jets1,
                                                       const float* __restrict__ jets2,
                                                       float* __restrict__ out) {
    const int l = threadIdx.x;
    const int b = blockIdx.x;
    const int q = l & 15;
    const int r = l >> 4;

    __shared__ double invDl[16 * 17];      // C[i][j] at i*17+j (stride-17)
    __shared__ double Sst[16 * 17];        // Schur staging (fallback path only)
    __shared__ double Lst[16 * 17];        // Lst[a*17+b] = L[b][a] (unit-diag L)
    __shared__ double Gst[2][16];          // rhs staging: [0]=R, [1]=I
    __shared__ double Ast[16];             // ar per row (MFMA A-scale)
    __shared__ double Bst[16];             // bb per column (diag add)

    const float* p1 = jets1 + b * 48;
    const float* p2 = jets2 + b * 48;

    double ax = (double)p1[3 * q], ay = (double)p1[3 * q + 1];
    double px[4];
#pragma unroll
    for (int c = 0; c < 4; c++) {
        int j = 4 * c + r;
        double d0 = ((double)p2[3 * j]     - ax) + 1e-12;
        double d1 = ((double)p2[3 * j + 1] - ay) + 1e-12;
        px[c] = sqrt(d0 * d0 + d1 * d1);
    }
    double h_rt = (double)p1[3 * q + 2];
    double h_ct[4];
#pragma unroll
    for (int c = 0; c < 4; c++) h_ct[c] = (double)p2[3 * (4 * c + r) + 2];

    double sw1 = sum16d(h_rt);
    double sw2 = sum16d((double)p2[3 * q + 2]);
    const double sB = fmin(sw1, sw2);
    const double sE = fabs(sw1 - sw2);

    // probe the permlane-swap output convention once (ISA-derived expectation:
    // ret0 = x[l&~m], ret1 = x[l|m]); fallback to LDS gather if it ever flips.
#if HAVE_PLSWAP
    auto pr16 = __builtin_amdgcn_permlane16_swap((unsigned)l, (unsigned)l, false, false);
    auto pr32 = __builtin_amdgcn_permlane32_swap((unsigned)l, (unsigned)l, false, false);
    const bool convOK = (__builtin_amdgcn_readfirstlane((int)pr16[0]) == 0) &&
                        (__builtin_amdgcn_readfirstlane((int)pr16[1]) == 16) &&
                        (__builtin_amdgcn_readfirstlane((int)pr32[0]) == 0) &&
                        (__builtin_amdgcn_readfirstlane((int)pr32[1]) == 32);
#else
    const bool convOK = false;
#endif

    // ---- one-time MFMA f64 fragment-layout self-test (exact integers) ----
    // A[i][k] = 100 i + k  (lane: i=q, k=r);  B[k][j] = 1000 k + j (k=r, j=q)
    // D[i][j] = sum_k (100 i + k)(1000 k + j) = 600000 i + 400 i j + 6 j + 14000
    // expected C/D layout: lane l reg g -> row 4*(l>>4)+g, col l&15.
    bool mfmaOK = false;
#if HAVE_MFMA64
    {
        double Aval = 100.0 * q + r;
        double Bval = 1000.0 * r + q;
        v4d accT = {0.0, 0.0, 0.0, 0.0};
        accT = __builtin_amdgcn_mfma_f64_16x16x4f64(Aval, Bval, accT, 0, 0, 0);
        bool ok = true;
#pragma unroll
        for (int g = 0; g < 4; g++) {
            double di = 4.0 * r + g, dj = (double)q;
            double expect = 600000.0 * di + 400.0 * di * dj + 6.0 * dj + 14000.0;
            ok = ok && (accT[g] == expect);
        }
        mfmaOK = (__all(ok ? 1 : 0) != 0) && convOK;
    }
#endif

    double x[4] = {0, 0, 0, 0}, s[4] = {1, 1, 1, 1}, z[4] = {1, 1, 1, 1};
    double yv = 0.0;
    double s_rt = 1.0, z_rt = 1.0;
    double s_ct[4] = {1, 1, 1, 1}, z_ct[4] = {1, 1, 1, 1};
    // incrementally-maintained sums of x (x starts at 0)
    double rsx = 0.0;                      // row-q sum of x
    double cs[4] = {0, 0, 0, 0};           // col 4c+r sums of x
    double ra = -sB;                       // sum(x) - sB

    for (int it = 0; it < NITER; ++it) {
        // ---- paired reciprocals + invDl stores (mu-independent; overlap the
        //      mu butterfly and bury the invDl lgkm latency) ----
        double prt = s_rt * z_rt;
        double irt = drcp(prt);
        double is_rt = z_rt * irt, iz_rt = s_rt * irt;
        double srz = (s_rt * s_rt) * irt;      // s_rt/z_rt
        double pct[4], is_ct[4], iz_ct[4];
#pragma unroll
        for (int c = 0; c < 4; c++) {
            pct[c] = s_ct[c] * z_ct[c];
            double ict = drcp(pct[c]);
            is_ct[c] = z_ct[c] * ict;
            iz_ct[c] = s_ct[c] * ict;
        }
        double szc[4], is_[4], iD[4];
#pragma unroll
        for (int c = 0; c < 4; c++) {
            szc[c] = s[c] * z[c];
            double tc = fma(L2C, s[c], z[c]);      // L2C*s + z
            double ip = drcp(s[c] * tc);
            is_[c] = tc * ip;                      // 1/s
            iD[c]  = (s[c] * s[c]) * ip;           // 1/(L2C + z/s)
            invDl[q * 17 + 4 * c + r] = iD[c];
        }

        // ---- mu = mean(s*z) over 288 (redundant copies scaled) ----
        double mub = szc[0] + szc[1] + szc[2] + szc[3]
                   + 0.25 * prt
                   + 0.0625 * (pct[0] + pct[1] + pct[2] + pct[3]);
        double mu = sum16d(cross4d(mub)) * (1.0 / 288.0);
        if (!(mu >= 1e-4)) break;   // gap ~ 288*mu ~ 2.9e-2 < 9.6e-2/2; catches NaN
        double sgmu = SIGC * mu;

        // ---- tail residuals (lane-local; rsx/cs maintained incrementally) ----
        double rp_rt = rsx + s_rt - h_rt;
        double rs_rt = prt - sgmu;
        double tt_rt = (z_rt * (rsx - h_rt) + sgmu) * is_rt;
        double rp_ct[4], rs_ct[4], tt_ct[4];
#pragma unroll
        for (int c = 0; c < 4; c++) {
            rp_ct[c] = cs[c] + s_ct[c] - h_ct[c];
            rs_ct[c] = pct[c] - sgmu;
            tt_ct[c] = (z_ct[c] * (cs[c] - h_ct[c]) + sgmu) * is_ct[c];
        }

        // ---- cell residuals ----
        double rp[4], rs[4], r1[4], rD1[4];
#pragma unroll
        for (int c = 0; c < 4; c++) {
            double rx = L2C * x[c] + px[c] + (-z[c] + z_rt + z_ct[c]) + yv;
            rp[c] = s[c] - x[c];
            rs[c] = szc[c] - sgmu;
            double tk = (sgmu - z[c] * x[c]) * is_[c];   // (z*rp - rs)/s
            r1[c] = rx - tk + tt_rt + tt_ct[c];
            rD1[c] = r1[c] * iD[c];
        }

        // ---- sums of invD, rD1 ----
        double rsI = cross4d(iD[0] + iD[1] + iD[2] + iD[3]);
        double rsR = cross4d(rD1[0] + rD1[1] + rD1[2] + rD1[3]);
        double csI[4];
#pragma unroll
        for (int c = 0; c < 4; c++) csI[c] = sum16d(iD[c]);

        double ar = drcp(srz + rsI);   // 1/A_q
        double aR = ar * rsR;
        double aI = ar * rsI;
        if (l < 16) Ast[l] = ar;       // stage ar per row (r==0 lanes cover q=0..15)

        // ---- rhs gp[j] = g_c[j] - sum_i aX_i*C[i][j]; gpR fused (linearity
        //      of sum16d: csR - sum(aR*iD) == sum(rD1 - aR*iD)) ----
        double bb[4];
#pragma unroll
        for (int c = 0; c < 4; c++) {
            double gpR = sum16d(rD1[c] - aR * iD[c]);
            double gpI = csI[c] - sum16d(aI * iD[c]);
            bb[c] = s_ct[c] * iz_ct[c] + csI[c];
            if (q == 4 * c + r) { Gst[0][q] = gpR; Gst[1][q] = gpI; Bst[q] = bb[c]; }
        }

        // ---- Schur S = diag(bb) - C^T diag(ar) C  (16x16x16 fp64 matmul) ----
        double Sr[16];
#if HAVE_MFMA64
        if (mfmaOK) {
            // A[i][k]=-ar_t*cell(t,i), B[k][j]=cell(t,j), t=4ch+k; per lane the
            // A and B values coincide at cell(4ch+r, q) (one b64 read/chunk).
            v4d acc = {0.0, 0.0, 0.0, 0.0};
#pragma unroll
            for (int ch = 0; ch < 4; ch++) {
                int t = 4 * ch + r;
                double cellv = invDl[t * 17 + q];
                double af = -(Ast[t] * cellv);
                acc = __builtin_amdgcn_mfma_f64_16x16x4f64(af, cellv, acc, 0, 0, 0);
            }
            // lane (q,r) reg g holds S'[4r+g][q] == S'[q][4r+g] (symmetry).
            // permlane butterfly -> full row q: Sr[4*rr+g] from r-group rr.
#pragma unroll
            for (int g = 0; g < 4; g++) {
                unsigned lo, hi; dsplit(acc[g], lo, hi);
                auto s16l = __builtin_amdgcn_permlane16_swap(lo, lo, false, false);
                auto s16h = __builtin_amdgcn_permlane16_swap(hi, hi, false, false);
                auto aL = __builtin_amdgcn_permlane32_swap(s16l[0], s16l[0], false, false);
                auto aH = __builtin_amdgcn_permlane32_swap(s16h[0], s16h[0], false, false);
                auto bL = __builtin_amdgcn_permlane32_swap(s16l[1], s16l[1], false, false);
                auto bH = __builtin_amdgcn_permlane32_swap(s16h[1], s16h[1], false, false);
                Sr[0 * 4 + g] = mkd(aL[0], aH[0]);   // rr=0
                Sr[2 * 4 + g] = mkd(aL[1], aH[1]);   // rr=2
                Sr[1 * 4 + g] = mkd(bL[0], bH[0]);   // rr=1
                Sr[3 * 4 + g] = mkd(bL[1], bH[1]);   // rr=3
            }
            Sr[q] += Bst[q];                         // diagonal
        } else
#endif
        {
            // fallback: R4 LDS path (split accumulators, chain depth 8)
            double accA[4] = {0, 0, 0, 0}, accB[4] = {0, 0, 0, 0};
#pragma unroll
            for (int t = 0; t < 8; t++) {
                double wA = rld(ar, t) * invDl[t * 17 + q];
                double wB = rld(ar, t + 8) * invDl[(t + 8) * 17 + q];
#pragma unroll
                for (int c = 0; c < 4; c++) {
                    accA[c] += wA * invDl[t * 17 + 4 * c + r];
                    accB[c] += wB * invDl[(t + 8) * 17 + 4 * c + r];
                }
            }
#pragma unroll
            for (int c = 0; c < 4; c++)
                Sst[q * 17 + 4 * c + r] = ((q == 4 * c + r) ? bb[c] : 0.0) - (accA[c] + accB[c]);
#pragma unroll
            for (int j2 = 0; j2 < 16; j2++) Sr[j2] = Sst[q * 17 + j2];
        }

        // ---- pivot floors precomputed (off the serial pivot chain) ----
        double flo[16];
#pragma unroll
        for (int kk = 0; kk < 16; kk++)
            flo[kk] = fmax(1e-12 * fabs(rld(Sr[kk], kk)), 1e-280);

        // ---- rhs read: one register per lane; r<2 carries R, r>=2 carries I ----
        double ysol = Gst[r >> 1][q];

        // ---- 16x16 LDLT (unit-diag L) + FUSED forward solve ----
        double invdv = 0.0;   // 1/d_q (own pivot) for the D-divide
        double pcand = 0.0;
#pragma unroll
        for (int kk = 0; kk < 16; kk++) {
            double praw = (kk == 0) ? rld(Sr[0], 0) : rld(pcand, kk);
            double dkk = fmax(praw, flo[kk]);
            double inv = drcp(dkk);
            invdv = (q == kk) ? inv : invdv;
            double Lc = Sr[kk] * inv;      // L[q][kk] (unit diag; valid q>=kk)
            if (l < 16) Lst[kk * 17 + l] = Lc;
            if (kk < 15) pcand = Sr[kk + 1] - Sr[kk] * Lc;   // lane-local next-pivot
            // fused forward solve (split halves, one fma)
            double t1 = rld(ysol, kk);
            double t2 = rld(ysol, kk + 32);
            double tt = (r < 2) ? t1 : t2;
            if (q > kk) ysol -= Lc * tt;
#pragma unroll
            for (int jj = kk + 1; jj < 16; jj++)
                Sr[jj] -= Sr[kk] * rld(Lc, jj);   // -= (L[q][kk]*d)*L[jj][kk]
            Sr[kk] = Lc;
        }

        // ---- D-divide (lane-local) ----
        ysol *= invdv;

        // ---- gather L^T row from LDS (issued before the bwd chain starts) ----
        double LTr[16];
#pragma unroll
        for (int kk = 0; kk < 16; kk++) LTr[kk] = Lst[q * 17 + kk];  // L[kk][q]

        // ---- backward solve L^T qc = v (split halves) ----
#pragma unroll
        for (int kk = 15; kk >= 0; kk--) {
            double t1 = rld(ysol, kk);
            double t2 = rld(ysol, kk + 32);
            double tt = (r < 2) ? t1 : t2;
            if (q < kk) ysol -= LTr[kk] * tt;
        }
        // lanes 0..15: ysol = qcR[q]; lanes 32..47: ysol = qcI[q]

        // ---- gather qc per own columns (sourced from the valid halves) ----
        double qc1c[4], qcvc[4];
#pragma unroll
        for (int c = 0; c < 4; c++) {
            qc1c[c] = __shfl(ysol, 4 * c + r, 64);
            qcvc[c] = __shfl(ysol, 32 + 4 * c + r, 64);
        }

        // ---- qr = ar*(g_r - sum_j C[q][j] qc_j) (cross4 reduction) ----
        double pr1 = iD[0]*qc1c[0] + iD[1]*qc1c[1] + iD[2]*qc1c[2] + iD[3]*qc1c[3];
        double prv = iD[0]*qcvc[0] + iD[1]*qcvc[1] + iD[2]*qcvc[2] + iD[3]*qcvc[3];
        double qr1 = ar * (rsR - cross4d(pr1));
        double qrv = ar * (rsI - cross4d(prv));

        // ---- u = H^{-1} r1, v = H^{-1} 1 ----
        double u[4], v[4];
#pragma unroll
        for (int c = 0; c < 4; c++) {
            u[c] = (r1[c] - qr1 - qc1c[c]) * iD[c];
            v[c] = (1.0  - qrv - qcvc[c]) * iD[c];
        }
        double urow = cross4d(u[0] + u[1] + u[2] + u[3]);
        double vrow = cross4d(v[0] + v[1] + v[2] + v[3]);
        double usum = sum16d(urow);
        double vsum = sum16d(vrow);
        double dy = (ra - usum) * drcp(vsum);

        // ---- dx + sums (rsdx reuses urow/vrow) ----
        double dx[4];
#pragma unroll
        for (int c = 0; c < 4; c++) dx[c] = -u[c] - v[c] * dy;
        double rsdx = -urow - vrow * dy;
        double csdx[4];
#pragma unroll
        for (int c = 0; c < 4; c++) csdx[c] = sum16d(dx[c]);
        double sumdx = -usum - vsum * dy;   // sum over all cells of dx (exact identity)

        // ---- ds, dz; SEPARATE primal/dual ratio tests (fp32, 0.99 margin) ----
        float amP = 1e30f, amD = 1e30f;
        double ds[4], dz[4];
#pragma unroll
        for (int c = 0; c < 4; c++) {
            ds[c] = dx[c] - rp[c];
            dz[c] = -(rs[c] + z[c] * ds[c]) * is_[c];
            if (ds[c] < 0.0) amP = fminf(amP, (float)s[c] * frcpf((float)(-ds[c])));
            if (dz[c] < 0.0) amD = fminf(amD, (float)z[c] * frcpf((float)(-dz[c])));
        }
        double ds_rt = -rp_rt - rsdx;
        double dz_rt = -(rs_rt + z_rt * ds_rt) * is_rt;
        if (ds_rt < 0.0) amP = fminf(amP, (float)s_rt * frcpf((float)(-ds_rt)));
        if (dz_rt < 0.0) amD = fminf(amD, (float)z_rt * frcpf((float)(-dz_rt)));
        double ds_ct[4], dz_ct[4];
#pragma unroll
        for (int c = 0; c < 4; c++) {
            ds_ct[c] = -rp_ct[c] - csdx[c];
            dz_ct[c] = -(rs_ct[c] + z_ct[c] * ds_ct[c]) * is_ct[c];
            if (ds_ct[c] < 0.0) amP = fminf(amP, (float)s_ct[c] * frcpf((float)(-ds_ct[c])));
            if (dz_ct[c] < 0.0) amD = fminf(amD, (float)z_ct[c] * frcpf((float)(-dz_ct[c])));
        }
        float aPf = min16f(cross4minf(amP));
        float aDf = min16f(cross4minf(amD));
        double alphaP = 0.99 * fmin(1.0, (double)aPf);
        double alphaD = 0.99 * fmin(1.0, (double)aDf);
        bool good = ((dy - dy) == 0.0);   // freeze on garbage direction
        alphaP = good ? alphaP : 0.0;
        alphaD = good ? alphaD : 0.0;

        // ---- step (x,s with alphaP; z,y with alphaD; x-sums incremental) ----
#pragma unroll
        for (int c = 0; c < 4; c++) {
            x[c] += alphaP * dx[c];
            s[c] += alphaP * ds[c];
            z[c] += alphaD * dz[c];
            s_ct[c] += alphaP * ds_ct[c];
            z_ct[c] += alphaD * dz_ct[c];
            cs[c] += alphaP * csdx[c];
        }
        yv += alphaD * dy;
        s_rt += alphaP * ds_rt;
        z_rt += alphaD * dz_rt;
        rsx += alphaP * rsdx;
        ra  += alphaP * sumdx;
    }

    // ---- emd = p.x + |sum w1 - sum w2| ----
    double e = sum16d(cross4d(px[0]*x[0] + px[1]*x[1] + px[2]*x[2] + px[3]*x[3]));
    if (l == 0) out[b] = (float)(e + sE);
}

extern "C" void kernel_launch(void* const* d_in, const int* in_sizes, int n_in,
                              void* d_out, int out_size, void* d_ws, size_t ws_size,
                              hipStream_t stream) {
    const float* jets1 = (const float*)d_in[0];
    const float* jets2 = (const float*)d_in[1];
    float* out = (float*)d_out;
    int B = in_sizes[0] / 48;   // 32
    emd_ip_kernel<<<dim3(B), dim3(64), 0, stream>>>(jets1, jets2, out);
}

// Round 9
// 112.106 us; speedup vs baseline: 1.3721x; 1.0064x over previous
//
#include <hip/hip_runtime.h>
#include <math.h>

#define L2C  1e-4
#define SIGC 0.1
#define NITER 20

// permlane swaps via builtins (R2-proven green; R0/R1 asm variants NaN'd:
// regalloc coalescing + unhandled VALU->permlane hazard inside asm blobs).
#if defined(__has_builtin)
#  if __has_builtin(__builtin_amdgcn_permlane16_swap) && __has_builtin(__builtin_amdgcn_permlane32_swap)
#    define HAVE_PLSWAP 1
#  endif
#  if __has_builtin(__builtin_amdgcn_rcp)
#    define HAVE_RCP64 1
#  endif
#  if __has_builtin(__builtin_amdgcn_mfma_f64_16x16x4f64)
#    define HAVE_MFMA64 1
#  endif
#endif
#ifndef HAVE_PLSWAP
#  define HAVE_PLSWAP 0
#endif
#ifndef HAVE_RCP64
#  define HAVE_RCP64 0
#endif
#ifndef HAVE_MFMA64
#  define HAVE_MFMA64 0
#endif

#if HAVE_MFMA64
typedef double v4d __attribute__((ext_vector_type(4)));
#endif

// ---- cross-lane helpers ----------------------------------------------------
__device__ __forceinline__ double rld(double v, int lane) {
    union { double d; int i[2]; } u, r; u.d = v;
    r.i[0] = __builtin_amdgcn_readlane(u.i[0], lane);
    r.i[1] = __builtin_amdgcn_readlane(u.i[1], lane);
    return r.d;
}
template <int CTRL>
__device__ __forceinline__ double dppd(double v) {
    union { double d; int i[2]; } u, r; u.d = v;
    r.i[0] = __builtin_amdgcn_update_dpp(0, u.i[0], CTRL, 0xF, 0xF, true);
    r.i[1] = __builtin_amdgcn_update_dpp(0, u.i[1], CTRL, 0xF, 0xF, true);
    return r.d;
}
// sum across each 16-lane DPP row (all lanes get the row total)
__device__ __forceinline__ double sum16d(double v) {
    v += dppd<0xB1>(v); v += dppd<0x4E>(v); v += dppd<0x124>(v); v += dppd<0x128>(v);
    return v;
}
template <int CTRL>
__device__ __forceinline__ float dppf(float v) {
    return __int_as_float(__builtin_amdgcn_update_dpp(0, __float_as_int(v), CTRL, 0xF, 0xF, true));
}
__device__ __forceinline__ float min16f(float v) {
    v = fminf(v, dppf<0xB1>(v)); v = fminf(v, dppf<0x4E>(v));
    v = fminf(v, dppf<0x124>(v)); v = fminf(v, dppf<0x128>(v));
    return v;
}
__device__ __forceinline__ float max16f(float v) {
    v = fmaxf(v, dppf<0xB1>(v)); v = fmaxf(v, dppf<0x4E>(v));
    v = fmaxf(v, dppf<0x124>(v)); v = fmaxf(v, dppf<0x128>(v));
    return v;
}
__device__ __forceinline__ double mkd(unsigned lo, unsigned hi) {
    union { unsigned u[2]; double d; } r; r.u[0] = lo; r.u[1] = hi; return r.d;
}
__device__ __forceinline__ void dsplit(double v, unsigned &lo, unsigned &hi) {
    union { double d; unsigned u[2]; } x; x.d = v; lo = x.u[0]; hi = x.u[1];
}
// combine the 4 16-lane rows (sum over {q, q+16, q+32, q+48}); order-independent.
__device__ __forceinline__ double cross4d(double v) {
#if HAVE_PLSWAP
    unsigned lo, hi; dsplit(v, lo, hi);
    auto rl = __builtin_amdgcn_permlane16_swap(lo, lo, false, false);
    auto rh = __builtin_amdgcn_permlane16_swap(hi, hi, false, false);
    v = mkd(rl[0], rh[0]) + mkd(rl[1], rh[1]);
    dsplit(v, lo, hi);
    auto sl = __builtin_amdgcn_permlane32_swap(lo, lo, false, false);
    auto sh = __builtin_amdgcn_permlane32_swap(hi, hi, false, false);
    return mkd(sl[0], sh[0]) + mkd(sl[1], sh[1]);
#else
    v += __shfl_xor(v, 16, 64); v += __shfl_xor(v, 32, 64); return v;
#endif
}
__device__ __forceinline__ float cross4minf(float v) {
#if HAVE_PLSWAP
    auto a = __builtin_amdgcn_permlane16_swap(__float_as_uint(v), __float_as_uint(v), false, false);
    v = fminf(__uint_as_float(a[0]), __uint_as_float(a[1]));
    auto b = __builtin_amdgcn_permlane32_swap(__float_as_uint(v), __float_as_uint(v), false, false);
    return fminf(__uint_as_float(b[0]), __uint_as_float(b[1]));
#else
    v = fminf(v, __shfl_xor(v, 16, 64)); v = fminf(v, __shfl_xor(v, 32, 64)); return v;
#endif
}
// fast fp64 reciprocal (v_rcp_f64 seed + one Newton), ~1e-14 rel err.
// R7 LESSON (measured, absmax 0.53 FAIL): raw v_rcp_f64 (~2^-26 rel err)
// without the Newton step is NOT enough for the direction math — iD reaches
// ~1/L2C=1e4 and the Schur/LDLT path carries condition ~1e6-8 as mu shrinks,
// amplifying seed error to O(0.1) absolute in the direction. Newton refine is
// REQUIRED wherever a reciprocal feeds H^{-1} (iD, pivots, ar). Keep this form.
__device__ __forceinline__ double drcp(double d) {
#if HAVE_RCP64
    double x = __builtin_amdgcn_rcp(d);
#else
    double x = (double)__builtin_amdgcn_rcpf((float)d);
#endif
    x = x * (2.0 - d * x);
    return x;
}
__device__ __forceinline__ float frcpf(float x) { return __builtin_amdgcn_rcpf(x); }

// One 64-lane wave per batch element; lane l: q=l&15, r=l>>4; owns cells
// (q, 4c+r). fp64 state, sigma=0.1, separate primal/dual steps, exit at
// mu<1e-4 (harness-proven numerics; R4 spine, R6 f64-MFMA Schur).
// R5 LESSON (measured): packing waves (2/SIMD) REGRESSED 62.5->102.7us —
// co-resident fp64-heavy waves contend. 1 wave/CU is the proven geometry.
// R8 = R6 numerics (Newton drcp restored) + R7's two SAFE trims kept:
// uniform scaled pivot floor 1e-12*max|S| (removes 32 readlanes + 48 f64
// from the spine; engages only at cond>1e12 where pivots are garbage anyway;
// good-freeze + mu-NaN break backstop) and Schur diag folded into the MFMA
// accumulator init (4 static cndmasks replace the 16-way dynamic select).
__global__ __launch_bounds__(64, 1) void emd_ip_kernel(const float* __restrict__ jets1,
                                                       const float* __restrict__ jets2,
                                                       float* __restrict__ out) {
    const int l = threadIdx.x;
    const int b = blockIdx.x;
    const int q = l & 15;
    const int r = l >> 4;

    __shared__ double invDl[16 * 17];      // C[i][j] at i*17+j (stride-17)
    __shared__ double Sst[16 * 17];        // Schur staging (fallback path only)
    __shared__ double Lst[16 * 17];        // Lst[a*17+b] = L[b][a] (unit-diag L)
    __shared__ double Gst[2][16];          // rhs staging: [0]=R, [1]=I
    __shared__ double Ast[16];             // ar per row (MFMA A-scale)
    __shared__ double Bst[16];             // bb per column (diag add)

    const float* p1 = jets1 + b * 48;
    const float* p2 = jets2 + b * 48;

    double ax = (double)p1[3 * q], ay = (double)p1[3 * q + 1];
    double px[4];
#pragma unroll
    for (int c = 0; c < 4; c++) {
        int j = 4 * c + r;
        double d0 = ((double)p2[3 * j]     - ax) + 1e-12;
        double d1 = ((double)p2[3 * j + 1] - ay) + 1e-12;
        px[c] = sqrt(d0 * d0 + d1 * d1);
    }
    double h_rt = (double)p1[3 * q + 2];
    double h_ct[4];
#pragma unroll
    for (int c = 0; c < 4; c++) h_ct[c] = (double)p2[3 * (4 * c + r) + 2];

    double sw1 = sum16d(h_rt);
    double sw2 = sum16d((double)p2[3 * q + 2]);
    const double sB = fmin(sw1, sw2);
    const double sE = fabs(sw1 - sw2);

    // probe the permlane-swap output convention once (ISA-derived expectation:
    // ret0 = x[l&~m], ret1 = x[l|m]); fallback to LDS gather if it ever flips.
#if HAVE_PLSWAP
    auto pr16 = __builtin_amdgcn_permlane16_swap((unsigned)l, (unsigned)l, false, false);
    auto pr32 = __builtin_amdgcn_permlane32_swap((unsigned)l, (unsigned)l, false, false);
    const bool convOK = (__builtin_amdgcn_readfirstlane((int)pr16[0]) == 0) &&
                        (__builtin_amdgcn_readfirstlane((int)pr16[1]) == 16) &&
                        (__builtin_amdgcn_readfirstlane((int)pr32[0]) == 0) &&
                        (__builtin_amdgcn_readfirstlane((int)pr32[1]) == 32);
#else
    const bool convOK = false;
#endif

    // ---- one-time MFMA f64 fragment-layout self-test (exact integers) ----
    bool mfmaOK = false;
#if HAVE_MFMA64
    {
        double Aval = 100.0 * q + r;
        double Bval = 1000.0 * r + q;
        v4d accT = {0.0, 0.0, 0.0, 0.0};
        accT = __builtin_amdgcn_mfma_f64_16x16x4f64(Aval, Bval, accT, 0, 0, 0);
        bool ok = true;
#pragma unroll
        for (int g = 0; g < 4; g++) {
            double di = 4.0 * r + g, dj = (double)q;
            double expect = 600000.0 * di + 400.0 * di * dj + 6.0 * dj + 14000.0;
            ok = ok && (accT[g] == expect);
        }
        mfmaOK = (__all(ok ? 1 : 0) != 0) && convOK;
    }
#endif

    double x[4] = {0, 0, 0, 0}, s[4] = {1, 1, 1, 1}, z[4] = {1, 1, 1, 1};
    double yv = 0.0;
    double s_rt = 1.0, z_rt = 1.0;
    double s_ct[4] = {1, 1, 1, 1}, z_ct[4] = {1, 1, 1, 1};
    // incrementally-maintained sums of x (x starts at 0)
    double rsx = 0.0;                      // row-q sum of x
    double cs[4] = {0, 0, 0, 0};           // col 4c+r sums of x
    double ra = -sB;                       // sum(x) - sB

    for (int it = 0; it < NITER; ++it) {
        // ---- paired reciprocals + invDl stores (mu-independent; overlap the
        //      mu butterfly and bury the invDl lgkm latency) ----
        double prt = s_rt * z_rt;
        double irt = drcp(prt);
        double is_rt = z_rt * irt, iz_rt = s_rt * irt;
        double srz = (s_rt * s_rt) * irt;      // s_rt/z_rt
        double pct[4], is_ct[4], iz_ct[4];
#pragma unroll
        for (int c = 0; c < 4; c++) {
            pct[c] = s_ct[c] * z_ct[c];
            double ict = drcp(pct[c]);
            is_ct[c] = z_ct[c] * ict;
            iz_ct[c] = s_ct[c] * ict;
        }
        double szc[4], is_[4], iD[4];
#pragma unroll
        for (int c = 0; c < 4; c++) {
            szc[c] = s[c] * z[c];
            double tc = fma(L2C, s[c], z[c]);      // L2C*s + z
            double ip = drcp(s[c] * tc);
            is_[c] = tc * ip;                      // 1/s
            iD[c]  = (s[c] * s[c]) * ip;           // 1/(L2C + z/s)
            invDl[q * 17 + 4 * c + r] = iD[c];
        }

        // ---- mu = mean(s*z) over 288 (redundant copies scaled) ----
        double mub = szc[0] + szc[1] + szc[2] + szc[3]
                   + 0.25 * prt
                   + 0.0625 * (pct[0] + pct[1] + pct[2] + pct[3]);
        double mu = sum16d(cross4d(mub)) * (1.0 / 288.0);
        if (!(mu >= 1e-4)) break;   // gap ~ 288*mu ~ 2.9e-2 < 9.6e-2/2; catches NaN
        double sgmu = SIGC * mu;

        // ---- tail residuals (lane-local; rsx/cs maintained incrementally) ----
        double rp_rt = rsx + s_rt - h_rt;
        double rs_rt = prt - sgmu;
        double tt_rt = (z_rt * (rsx - h_rt) + sgmu) * is_rt;
        double rp_ct[4], rs_ct[4], tt_ct[4];
#pragma unroll
        for (int c = 0; c < 4; c++) {
            rp_ct[c] = cs[c] + s_ct[c] - h_ct[c];
            rs_ct[c] = pct[c] - sgmu;
            tt_ct[c] = (z_ct[c] * (cs[c] - h_ct[c]) + sgmu) * is_ct[c];
        }

        // ---- cell residuals ----
        double rp[4], rs[4], r1[4], rD1[4];
#pragma unroll
        for (int c = 0; c < 4; c++) {
            double rx = L2C * x[c] + px[c] + (-z[c] + z_rt + z_ct[c]) + yv;
            rp[c] = s[c] - x[c];
            rs[c] = szc[c] - sgmu;
            double tk = (sgmu - z[c] * x[c]) * is_[c];   // (z*rp - rs)/s
            r1[c] = rx - tk + tt_rt + tt_ct[c];
            rD1[c] = r1[c] * iD[c];
        }

        // ---- sums of invD, rD1 ----
        double rsI = cross4d(iD[0] + iD[1] + iD[2] + iD[3]);
        double rsR = cross4d(rD1[0] + rD1[1] + rD1[2] + rD1[3]);
        double csI[4];
#pragma unroll
        for (int c = 0; c < 4; c++) csI[c] = sum16d(iD[c]);

        double ar = drcp(srz + rsI);   // 1/A_q
        double aR = ar * rsR;
        double aI = ar * rsI;
        if (l < 16) Ast[l] = ar;       // stage ar per row (r==0 lanes cover q=0..15)

        // ---- rhs gp[j] = g_c[j] - sum_i aX_i*C[i][j]; gpR fused (linearity
        //      of sum16d: csR - sum(aR*iD) == sum(rD1 - aR*iD)) ----
        double bb[4];
#pragma unroll
        for (int c = 0; c < 4; c++) {
            double gpR = sum16d(rD1[c] - aR * iD[c]);
            double gpI = csI[c] - sum16d(aI * iD[c]);
            bb[c] = s_ct[c] * iz_ct[c] + csI[c];
            if (q == 4 * c + r) { Gst[0][q] = gpR; Gst[1][q] = gpI; Bst[q] = bb[c]; }
        }

        // ---- Schur S = diag(bb) - C^T diag(ar) C  (16x16x16 fp64 matmul) ----
        double Sr[16];
#if HAVE_MFMA64
        if (mfmaOK) {
            // A[i][k]=-ar_t*cell(t,i), B[k][j]=cell(t,j), t=4ch+k; per lane the
            // A and B values coincide at cell(4ch+r, q) (one b64 read/chunk).
            // diag(bb) folded into the accumulator init: acc[g] is (row 4r+g,
            // col q) -> bb on the diagonal (4 static cndmasks).
            double bbq = Bst[q];
            v4d acc;
#pragma unroll
            for (int g = 0; g < 4; g++) acc[g] = (4 * r + g == q) ? bbq : 0.0;
#pragma unroll
            for (int ch = 0; ch < 4; ch++) {
                int t = 4 * ch + r;
                double cellv = invDl[t * 17 + q];
                double af = -(Ast[t] * cellv);
                acc = __builtin_amdgcn_mfma_f64_16x16x4f64(af, cellv, acc, 0, 0, 0);
            }
            // lane (q,r) reg g holds S[4r+g][q] == S[q][4r+g] (symmetry).
            // permlane butterfly -> full row q: Sr[4*rr+g] from r-group rr.
#pragma unroll
            for (int g = 0; g < 4; g++) {
                unsigned lo, hi; dsplit(acc[g], lo, hi);
                auto s16l = __builtin_amdgcn_permlane16_swap(lo, lo, false, false);
                auto s16h = __builtin_amdgcn_permlane16_swap(hi, hi, false, false);
                auto aL = __builtin_amdgcn_permlane32_swap(s16l[0], s16l[0], false, false);
                auto aH = __builtin_amdgcn_permlane32_swap(s16h[0], s16h[0], false, false);
                auto bL = __builtin_amdgcn_permlane32_swap(s16l[1], s16l[1], false, false);
                auto bH = __builtin_amdgcn_permlane32_swap(s16h[1], s16h[1], false, false);
                Sr[0 * 4 + g] = mkd(aL[0], aH[0]);   // rr=0
                Sr[2 * 4 + g] = mkd(aL[1], aH[1]);   // rr=2
                Sr[1 * 4 + g] = mkd(bL[0], bH[0]);   // rr=1
                Sr[3 * 4 + g] = mkd(bL[1], bH[1]);   // rr=3
            }
        } else
#endif
        {
            // fallback: R4 LDS path (split accumulators, chain depth 8)
            double accA[4] = {0, 0, 0, 0}, accB[4] = {0, 0, 0, 0};
#pragma unroll
            for (int t = 0; t < 8; t++) {
                double wA = rld(ar, t) * invDl[t * 17 + q];
                double wB = rld(ar, t + 8) * invDl[(t + 8) * 17 + q];
#pragma unroll
                for (int c = 0; c < 4; c++) {
                    accA[c] += wA * invDl[t * 17 + 4 * c + r];
                    accB[c] += wB * invDl[(t + 8) * 17 + 4 * c + r];
                }
            }
#pragma unroll
            for (int c = 0; c < 4; c++)
                Sst[q * 17 + 4 * c + r] = ((q == 4 * c + r) ? bb[c] : 0.0) - (accA[c] + accB[c]);
#pragma unroll
            for (int j2 = 0; j2 < 16; j2++) Sr[j2] = Sst[q * 17 + j2];
        }

        // ---- uniform scaled pivot floor: 1e-12 * max|S| ----
        double mrow = fabs(Sr[0]);
#pragma unroll
        for (int j2 = 1; j2 < 16; j2++) mrow = fmax(mrow, fabs(Sr[j2]));
        float mf = max16f((float)mrow);
        const double flo = fmax(1e-12 * (double)mf, 1e-280);

        // ---- rhs read: one register per lane; r<2 carries R, r>=2 carries I ----
        double ysol = Gst[r >> 1][q];

        // ---- 16x16 LDLT (unit-diag L) + FUSED forward solve ----
        double invdv = 0.0;   // 1/d_q (own pivot) for the D-divide
        double pcand = 0.0;
#pragma unroll
        for (int kk = 0; kk < 16; kk++) {
            double praw = (kk == 0) ? rld(Sr[0], 0) : rld(pcand, kk);
            double dkk = fmax(praw, flo);
            double inv = drcp(dkk);
            invdv = (q == kk) ? inv : invdv;
            double Lc = Sr[kk] * inv;      // L[q][kk] (unit diag; valid q>=kk)
            if (l < 16) Lst[kk * 17 + l] = Lc;
            if (kk < 15) pcand = Sr[kk + 1] - Sr[kk] * Lc;   // lane-local next-pivot
            // fused forward solve (split halves, one fma)
            double t1 = rld(ysol, kk);
            double t2 = rld(ysol, kk + 32);
            double tt = (r < 2) ? t1 : t2;
            if (q > kk) ysol -= Lc * tt;
#pragma unroll
            for (int jj = kk + 1; jj < 16; jj++)
                Sr[jj] -= Sr[kk] * rld(Lc, jj);   // -= (L[q][kk]*d)*L[jj][kk]
            Sr[kk] = Lc;
        }

        // ---- D-divide (lane-local) ----
        ysol *= invdv;

        // ---- gather L^T row from LDS (issued before the bwd chain starts) ----
        double LTr[16];
#pragma unroll
        for (int kk = 0; kk < 16; kk++) LTr[kk] = Lst[q * 17 + kk];  // L[kk][q]

        // ---- backward solve L^T qc = v (split halves) ----
#pragma unroll
        for (int kk = 15; kk >= 0; kk--) {
            double t1 = rld(ysol, kk);
            double t2 = rld(ysol, kk + 32);
            double tt = (r < 2) ? t1 : t2;
            if (q < kk) ysol -= LTr[kk] * tt;
        }
        // lanes 0..15: ysol = qcR[q]; lanes 32..47: ysol = qcI[q]

        // ---- gather qc per own columns (sourced from the valid halves) ----
        double qc1c[4], qcvc[4];
#pragma unroll
        for (int c = 0; c < 4; c++) {
            qc1c[c] = __shfl(ysol, 4 * c + r, 64);
            qcvc[c] = __shfl(ysol, 32 + 4 * c + r, 64);
        }

        // ---- qr = ar*(g_r - sum_j C[q][j] qc_j) (cross4 reduction) ----
        double pr1 = iD[0]*qc1c[0] + iD[1]*qc1c[1] + iD[2]*qc1c[2] + iD[3]*qc1c[3];
        double prv = iD[0]*qcvc[0] + iD[1]*qcvc[1] + iD[2]*qcvc[2] + iD[3]*qcvc[3];
        double qr1 = ar * (rsR - cross4d(pr1));
        double qrv = ar * (rsI - cross4d(prv));

        // ---- u = H^{-1} r1, v = H^{-1} 1 ----
        double u[4], v[4];
#pragma unroll
        for (int c = 0; c < 4; c++) {
            u[c] = (r1[c] - qr1 - qc1c[c]) * iD[c];
            v[c] = (1.0  - qrv - qcvc[c]) * iD[c];
        }
        double urow = cross4d(u[0] + u[1] + u[2] + u[3]);
        double vrow = cross4d(v[0] + v[1] + v[2] + v[3]);
        double usum = sum16d(urow);
        double vsum = sum16d(vrow);
        double dy = (ra - usum) * drcp(vsum);

        // ---- dx + sums (rsdx reuses urow/vrow) ----
        double dx[4];
#pragma unroll
        for (int c = 0; c < 4; c++) dx[c] = -u[c] - v[c] * dy;
        double rsdx = -urow - vrow * dy;
        double csdx[4];
#pragma unroll
        for (int c = 0; c < 4; c++) csdx[c] = sum16d(dx[c]);
        double sumdx = -usum - vsum * dy;   // sum over all cells of dx (exact identity)

        // ---- ds, dz; SEPARATE primal/dual ratio tests (fp32, 0.99 margin) ----
        float amP = 1e30f, amD = 1e30f;
        double ds[4], dz[4];
#pragma unroll
        for (int c = 0; c < 4; c++) {
            ds[c] = dx[c] - rp[c];
            dz[c] = -(rs[c] + z[c] * ds[c]) * is_[c];
            if (ds[c] < 0.0) amP = fminf(amP, (float)s[c] * frcpf((float)(-ds[c])));
            if (dz[c] < 0.0) amD = fminf(amD, (float)z[c] * frcpf((float)(-dz[c])));
        }
        double ds_rt = -rp_rt - rsdx;
        double dz_rt = -(rs_rt + z_rt * ds_rt) * is_rt;
        if (ds_rt < 0.0) amP = fminf(amP, (float)s_rt * frcpf((float)(-ds_rt)));
        if (dz_rt < 0.0) amD = fminf(amD, (float)z_rt * frcpf((float)(-dz_rt)));
        double ds_ct[4], dz_ct[4];
#pragma unroll
        for (int c = 0; c < 4; c++) {
            ds_ct[c] = -rp_ct[c] - csdx[c];
            dz_ct[c] = -(rs_ct[c] + z_ct[c] * ds_ct[c]) * is_ct[c];
            if (ds_ct[c] < 0.0) amP = fminf(amP, (float)s_ct[c] * frcpf((float)(-ds_ct[c])));
            if (dz_ct[c] < 0.0) amD = fminf(amD, (float)z_ct[c] * frcpf((float)(-dz_ct[c])));
        }
        float aPf = min16f(cross4minf(amP));
        float aDf = min16f(cross4minf(amD));
        double alphaP = 0.99 * fmin(1.0, (double)aPf);
        double alphaD = 0.99 * fmin(1.0, (double)aDf);
        bool good = ((dy - dy) == 0.0);   // freeze on garbage direction
        alphaP = good ? alphaP : 0.0;
        alphaD = good ? alphaD : 0.0;

        // ---- step (x,s with alphaP; z,y with alphaD; x-sums incremental) ----
#pragma unroll
        for (int c = 0; c < 4; c++) {
            x[c] += alphaP * dx[c];
            s[c] += alphaP * ds[c];
            z[c] += alphaD * dz[c];
            s_ct[c] += alphaP * ds_ct[c];
            z_ct[c] += alphaD * dz_ct[c];
            cs[c] += alphaP * csdx[c];
        }
        yv += alphaD * dy;
        s_rt += alphaP * ds_rt;
        z_rt += alphaD * dz_rt;
        rsx += alphaP * rsdx;
        ra  += alphaP * sumdx;
    }

    // ---- emd = p.x + |sum w1 - sum w2| ----
    double e = sum16d(cross4d(px[0]*x[0] + px[1]*x[1] + px[2]*x[2] + px[3]*x[3]));
    if (l == 0) out[b] = (float)(e + sE);
}

extern "C" void kernel_launch(void* const* d_in, const int* in_sizes, int n_in,
                              void* d_out, int out_size, void* d_ws, size_t ws_size,
                              hipStream_t stream) {
    const float* jets1 = (const float*)d_in[0];
    const float* jets2 = (const float*)d_in[1];
    float* out = (float*)d_out;
    int B = in_sizes[0] / 48;   // 32
    emd_ip_kernel<<<dim3(B), dim3(64), 0, stream>>>(jets1, jets2, out);
}

// Round 10
// 111.894 us; speedup vs baseline: 1.3747x; 1.0019x over previous
//
#include <hip/hip_runtime.h>
#include <math.h>

#define L2C  1e-4
#define SIGC 0.1
#define NITER 20

// permlane swaps via builtins (R2-proven green; R0/R1 asm variants NaN'd:
// regalloc coalescing + unhandled VALU->permlane hazard inside asm blobs).
#if defined(__has_builtin)
#  if __has_builtin(__builtin_amdgcn_permlane16_swap) && __has_builtin(__builtin_amdgcn_permlane32_swap)
#    define HAVE_PLSWAP 1
#  endif
#  if __has_builtin(__builtin_amdgcn_rcp)
#    define HAVE_RCP64 1
#  endif
#  if __has_builtin(__builtin_amdgcn_mfma_f64_16x16x4f64)
#    define HAVE_MFMA64 1
#  endif
#endif
#ifndef HAVE_PLSWAP
#  define HAVE_PLSWAP 0
#endif
#ifndef HAVE_RCP64
#  define HAVE_RCP64 0
#endif
#ifndef HAVE_MFMA64
#  define HAVE_MFMA64 0
#endif

#if HAVE_MFMA64
typedef double v4d __attribute__((ext_vector_type(4)));
#endif

// ---- cross-lane helpers ----------------------------------------------------
__device__ __forceinline__ double rld(double v, int lane) {
    union { double d; int i[2]; } u, r; u.d = v;
    r.i[0] = __builtin_amdgcn_readlane(u.i[0], lane);
    r.i[1] = __builtin_amdgcn_readlane(u.i[1], lane);
    return r.d;
}
template <int CTRL>
__device__ __forceinline__ double dppd(double v) {
    union { double d; int i[2]; } u, r; u.d = v;
    r.i[0] = __builtin_amdgcn_update_dpp(0, u.i[0], CTRL, 0xF, 0xF, true);
    r.i[1] = __builtin_amdgcn_update_dpp(0, u.i[1], CTRL, 0xF, 0xF, true);
    return r.d;
}
// sum across each 16-lane DPP row (all lanes get the row total)
__device__ __forceinline__ double sum16d(double v) {
    v += dppd<0xB1>(v); v += dppd<0x4E>(v); v += dppd<0x124>(v); v += dppd<0x128>(v);
    return v;
}
template <int CTRL>
__device__ __forceinline__ float dppf(float v) {
    return __int_as_float(__builtin_amdgcn_update_dpp(0, __float_as_int(v), CTRL, 0xF, 0xF, true));
}
__device__ __forceinline__ float min16f(float v) {
    v = fminf(v, dppf<0xB1>(v)); v = fminf(v, dppf<0x4E>(v));
    v = fminf(v, dppf<0x124>(v)); v = fminf(v, dppf<0x128>(v));
    return v;
}
__device__ __forceinline__ float max16f(float v) {
    v = fmaxf(v, dppf<0xB1>(v)); v = fmaxf(v, dppf<0x4E>(v));
    v = fmaxf(v, dppf<0x124>(v)); v = fmaxf(v, dppf<0x128>(v));
    return v;
}
__device__ __forceinline__ double mkd(unsigned lo, unsigned hi) {
    union { unsigned u[2]; double d; } r; r.u[0] = lo; r.u[1] = hi; return r.d;
}
__device__ __forceinline__ void dsplit(double v, unsigned &lo, unsigned &hi) {
    union { double d; unsigned u[2]; } x; x.d = v; lo = x.u[0]; hi = x.u[1];
}
// combine the 4 16-lane rows (sum over {q, q+16, q+32, q+48}); order-independent.
__device__ __forceinline__ double cross4d(double v) {
#if HAVE_PLSWAP
    unsigned lo, hi; dsplit(v, lo, hi);
    auto rl = __builtin_amdgcn_permlane16_swap(lo, lo, false, false);
    auto rh = __builtin_amdgcn_permlane16_swap(hi, hi, false, false);
    v = mkd(rl[0], rh[0]) + mkd(rl[1], rh[1]);
    dsplit(v, lo, hi);
    auto sl = __builtin_amdgcn_permlane32_swap(lo, lo, false, false);
    auto sh = __builtin_amdgcn_permlane32_swap(hi, hi, false, false);
    return mkd(sl[0], sh[0]) + mkd(sl[1], sh[1]);
#else
    v += __shfl_xor(v, 16, 64); v += __shfl_xor(v, 32, 64); return v;
#endif
}
__device__ __forceinline__ float cross4minf(float v) {
#if HAVE_PLSWAP
    auto a = __builtin_amdgcn_permlane16_swap(__float_as_uint(v), __float_as_uint(v), false, false);
    v = fminf(__uint_as_float(a[0]), __uint_as_float(a[1]));
    auto b = __builtin_amdgcn_permlane32_swap(__float_as_uint(v), __float_as_uint(v), false, false);
    return fminf(__uint_as_float(b[0]), __uint_as_float(b[1]));
#else
    v = fminf(v, __shfl_xor(v, 16, 64)); v = fminf(v, __shfl_xor(v, 32, 64)); return v;
#endif
}
// fast fp64 reciprocal (v_rcp_f64 seed + one Newton), ~1e-14 rel err.
// R7 LESSON (measured, absmax 0.53 FAIL): raw v_rcp_f64 (~2^-26 rel err)
// without the Newton step is NOT enough for the direction math — iD reaches
// ~1/L2C=1e4 and the Schur/LDLT path carries condition ~1e6-8 as mu shrinks.
// Newton refine is REQUIRED wherever a reciprocal feeds H^{-1}.
__device__ __forceinline__ double drcp(double d) {
#if HAVE_RCP64
    double x = __builtin_amdgcn_rcp(d);
#else
    double x = (double)__builtin_amdgcn_rcpf((float)d);
#endif
    x = x * (2.0 - d * x);
    return x;
}
__device__ __forceinline__ float frcpf(float x) { return __builtin_amdgcn_rcpf(x); }

// One 64-lane wave per batch element; lane l: q=l&15, r=l>>4; owns cells
// (q, 4c+r). fp64 state, sigma=0.1, separate primal/dual steps, exit at
// mu<1e-4 (harness-proven numerics; R4 spine, R6 f64-MFMA Schur, R8 floor).
// R5 LESSON (measured): packing waves (2/SIMD) REGRESSED 62.5->102.7us —
// co-resident fp64-heavy waves contend. 1 wave/CU is the proven geometry.
// R9: 2x2-BLOCK LDLT. S is SPD (Schur complement of an SPD system) so an
// unpivoted block-LDLT with 2x2 diagonal blocks is sound: 8 serial blocks
// replace 16 serial pivots — drcp count on the spine halves (16->8, each
// still Newton-refined per R7's lesson), and the backward solve depth also
// halves (8 dependent rank-2 steps). Exactness notes: L[k1][k0] = (b*c-c*b)
// *idet == exact 0; block D-divide is lane-local 2-coeff (m0*w_self +
// m1*w_partner) with the partner fetched by one DPP quad_perm [1,0,3,2]
// (lane l^1). det floored at max(flo^2, 1e-280) (flo = 1e-12*max|S|).
__global__ __launch_bounds__(64, 1) void emd_ip_kernel(const float* __restrict__ jets1,
                                                       const float* __restrict__ jets2,
                                                       float* __restrict__ out) {
    const int l = threadIdx.x;
    const int b = blockIdx.x;
    const int q = l & 15;
    const int r = l >> 4;

    __shared__ double invDl[16 * 17];      // C[i][j] at i*17+j (stride-17)
    __shared__ double Sst[16 * 17];        // Schur staging (fallback path only)
    __shared__ double Lst[16 * 17];        // Lst[a*17+b] = L[b][a] (unit-diag L)
    __shared__ double Gst[2][16];          // rhs staging: [0]=R, [1]=I
    __shared__ double Ast[16];             // ar per row (MFMA A-scale)
    __shared__ double Bst[16];             // bb per column (diag add)

    const float* p1 = jets1 + b * 48;
    const float* p2 = jets2 + b * 48;

    double ax = (double)p1[3 * q], ay = (double)p1[3 * q + 1];
    double px[4];
#pragma unroll
    for (int c = 0; c < 4; c++) {
        int j = 4 * c + r;
        double d0 = ((double)p2[3 * j]     - ax) + 1e-12;
        double d1 = ((double)p2[3 * j + 1] - ay) + 1e-12;
        px[c] = sqrt(d0 * d0 + d1 * d1);
    }
    double h_rt = (double)p1[3 * q + 2];
    double h_ct[4];
#pragma unroll
    for (int c = 0; c < 4; c++) h_ct[c] = (double)p2[3 * (4 * c + r) + 2];

    double sw1 = sum16d(h_rt);
    double sw2 = sum16d((double)p2[3 * q + 2]);
    const double sB = fmin(sw1, sw2);
    const double sE = fabs(sw1 - sw2);

    // probe the permlane-swap output convention once (ISA-derived expectation:
    // ret0 = x[l&~m], ret1 = x[l|m]); fallback to LDS gather if it ever flips.
#if HAVE_PLSWAP
    auto pr16 = __builtin_amdgcn_permlane16_swap((unsigned)l, (unsigned)l, false, false);
    auto pr32 = __builtin_amdgcn_permlane32_swap((unsigned)l, (unsigned)l, false, false);
    const bool convOK = (__builtin_amdgcn_readfirstlane((int)pr16[0]) == 0) &&
                        (__builtin_amdgcn_readfirstlane((int)pr16[1]) == 16) &&
                        (__builtin_amdgcn_readfirstlane((int)pr32[0]) == 0) &&
                        (__builtin_amdgcn_readfirstlane((int)pr32[1]) == 32);
#else
    const bool convOK = false;
#endif

    // ---- one-time MFMA f64 fragment-layout self-test (exact integers) ----
    bool mfmaOK = false;
#if HAVE_MFMA64
    {
        double Aval = 100.0 * q + r;
        double Bval = 1000.0 * r + q;
        v4d accT = {0.0, 0.0, 0.0, 0.0};
        accT = __builtin_amdgcn_mfma_f64_16x16x4f64(Aval, Bval, accT, 0, 0, 0);
        bool ok = true;
#pragma unroll
        for (int g = 0; g < 4; g++) {
            double di = 4.0 * r + g, dj = (double)q;
            double expect = 600000.0 * di + 400.0 * di * dj + 6.0 * dj + 14000.0;
            ok = ok && (accT[g] == expect);
        }
        mfmaOK = (__all(ok ? 1 : 0) != 0) && convOK;
    }
#endif

    double x[4] = {0, 0, 0, 0}, s[4] = {1, 1, 1, 1}, z[4] = {1, 1, 1, 1};
    double yv = 0.0;
    double s_rt = 1.0, z_rt = 1.0;
    double s_ct[4] = {1, 1, 1, 1}, z_ct[4] = {1, 1, 1, 1};
    // incrementally-maintained sums of x (x starts at 0)
    double rsx = 0.0;                      // row-q sum of x
    double cs[4] = {0, 0, 0, 0};           // col 4c+r sums of x
    double ra = -sB;                       // sum(x) - sB

    for (int it = 0; it < NITER; ++it) {
        // ---- paired reciprocals + invDl stores (mu-independent; overlap the
        //      mu butterfly and bury the invDl lgkm latency) ----
        double prt = s_rt * z_rt;
        double irt = drcp(prt);
        double is_rt = z_rt * irt, iz_rt = s_rt * irt;
        double srz = (s_rt * s_rt) * irt;      // s_rt/z_rt
        double pct[4], is_ct[4], iz_ct[4];
#pragma unroll
        for (int c = 0; c < 4; c++) {
            pct[c] = s_ct[c] * z_ct[c];
            double ict = drcp(pct[c]);
            is_ct[c] = z_ct[c] * ict;
            iz_ct[c] = s_ct[c] * ict;
        }
        double szc[4], is_[4], iD[4];
#pragma unroll
        for (int c = 0; c < 4; c++) {
            szc[c] = s[c] * z[c];
            double tc = fma(L2C, s[c], z[c]);      // L2C*s + z
            double ip = drcp(s[c] * tc);
            is_[c] = tc * ip;                      // 1/s
            iD[c]  = (s[c] * s[c]) * ip;           // 1/(L2C + z/s)
            invDl[q * 17 + 4 * c + r] = iD[c];
        }

        // ---- mu = mean(s*z) over 288 (redundant copies scaled) ----
        double mub = szc[0] + szc[1] + szc[2] + szc[3]
                   + 0.25 * prt
                   + 0.0625 * (pct[0] + pct[1] + pct[2] + pct[3]);
        double mu = sum16d(cross4d(mub)) * (1.0 / 288.0);
        if (!(mu >= 1e-4)) break;   // gap ~ 288*mu ~ 2.9e-2 < 9.6e-2/2; catches NaN
        double sgmu = SIGC * mu;

        // ---- tail residuals (lane-local; rsx/cs maintained incrementally) ----
        double rp_rt = rsx + s_rt - h_rt;
        double rs_rt = prt - sgmu;
        double tt_rt = (z_rt * (rsx - h_rt) + sgmu) * is_rt;
        double rp_ct[4], rs_ct[4], tt_ct[4];
#pragma unroll
        for (int c = 0; c < 4; c++) {
            rp_ct[c] = cs[c] + s_ct[c] - h_ct[c];
            rs_ct[c] = pct[c] - sgmu;
            tt_ct[c] = (z_ct[c] * (cs[c] - h_ct[c]) + sgmu) * is_ct[c];
        }

        // ---- cell residuals ----
        double rp[4], rs[4], r1[4], rD1[4];
#pragma unroll
        for (int c = 0; c < 4; c++) {
            double rx = L2C * x[c] + px[c] + (-z[c] + z_rt + z_ct[c]) + yv;
            rp[c] = s[c] - x[c];
            rs[c] = szc[c] - sgmu;
            double tk = (sgmu - z[c] * x[c]) * is_[c];   // (z*rp - rs)/s
            r1[c] = rx - tk + tt_rt + tt_ct[c];
            rD1[c] = r1[c] * iD[c];
        }

        // ---- sums of invD, rD1 ----
        double rsI = cross4d(iD[0] + iD[1] + iD[2] + iD[3]);
        double rsR = cross4d(rD1[0] + rD1[1] + rD1[2] + rD1[3]);
        double csI[4];
#pragma unroll
        for (int c = 0; c < 4; c++) csI[c] = sum16d(iD[c]);

        double ar = drcp(srz + rsI);   // 1/A_q
        double aR = ar * rsR;
        double aI = ar * rsI;
        if (l < 16) Ast[l] = ar;       // stage ar per row (r==0 lanes cover q=0..15)

        // ---- rhs gp[j] = g_c[j] - sum_i aX_i*C[i][j]; gpR fused (linearity
        //      of sum16d: csR - sum(aR*iD) == sum(rD1 - aR*iD)) ----
        double bb[4];
#pragma unroll
        for (int c = 0; c < 4; c++) {
            double gpR = sum16d(rD1[c] - aR * iD[c]);
            double gpI = csI[c] - sum16d(aI * iD[c]);
            bb[c] = s_ct[c] * iz_ct[c] + csI[c];
            if (q == 4 * c + r) { Gst[0][q] = gpR; Gst[1][q] = gpI; Bst[q] = bb[c]; }
        }

        // ---- Schur S = diag(bb) - C^T diag(ar) C  (16x16x16 fp64 matmul) ----
        double Sr[16];
#if HAVE_MFMA64
        if (mfmaOK) {
            // A[i][k]=-ar_t*cell(t,i), B[k][j]=cell(t,j), t=4ch+k; per lane the
            // A and B values coincide at cell(4ch+r, q) (one b64 read/chunk).
            // diag(bb) folded into the accumulator init (4 static cndmasks).
            double bbq = Bst[q];
            v4d acc;
#pragma unroll
            for (int g = 0; g < 4; g++) acc[g] = (4 * r + g == q) ? bbq : 0.0;
#pragma unroll
            for (int ch = 0; ch < 4; ch++) {
                int t = 4 * ch + r;
                double cellv = invDl[t * 17 + q];
                double af = -(Ast[t] * cellv);
                acc = __builtin_amdgcn_mfma_f64_16x16x4f64(af, cellv, acc, 0, 0, 0);
            }
            // lane (q,r) reg g holds S[4r+g][q] == S[q][4r+g] (symmetry).
            // permlane butterfly -> full row q: Sr[4*rr+g] from r-group rr.
#pragma unroll
            for (int g = 0; g < 4; g++) {
                unsigned lo, hi; dsplit(acc[g], lo, hi);
                auto s16l = __builtin_amdgcn_permlane16_swap(lo, lo, false, false);
                auto s16h = __builtin_amdgcn_permlane16_swap(hi, hi, false, false);
                auto aL = __builtin_amdgcn_permlane32_swap(s16l[0], s16l[0], false, false);
                auto aH = __builtin_amdgcn_permlane32_swap(s16h[0], s16h[0], false, false);
                auto bL = __builtin_amdgcn_permlane32_swap(s16l[1], s16l[1], false, false);
                auto bH = __builtin_amdgcn_permlane32_swap(s16h[1], s16h[1], false, false);
                Sr[0 * 4 + g] = mkd(aL[0], aH[0]);   // rr=0
                Sr[2 * 4 + g] = mkd(aL[1], aH[1]);   // rr=2
                Sr[1 * 4 + g] = mkd(bL[0], bH[0]);   // rr=1
                Sr[3 * 4 + g] = mkd(bL[1], bH[1]);   // rr=3
            }
        } else
#endif
        {
            // fallback: R4 LDS path (split accumulators, chain depth 8)
            double accA[4] = {0, 0, 0, 0}, accB[4] = {0, 0, 0, 0};
#pragma unroll
            for (int t = 0; t < 8; t++) {
                double wA = rld(ar, t) * invDl[t * 17 + q];
                double wB = rld(ar, t + 8) * invDl[(t + 8) * 17 + q];
#pragma unroll
                for (int c = 0; c < 4; c++) {
                    accA[c] += wA * invDl[t * 17 + 4 * c + r];
                    accB[c] += wB * invDl[(t + 8) * 17 + 4 * c + r];
                }
            }
#pragma unroll
            for (int c = 0; c < 4; c++)
                Sst[q * 17 + 4 * c + r] = ((q == 4 * c + r) ? bb[c] : 0.0) - (accA[c] + accB[c]);
#pragma unroll
            for (int j2 = 0; j2 < 16; j2++) Sr[j2] = Sst[q * 17 + j2];
        }

        // ---- uniform scaled pivot floor: det >= max((1e-12*max|S|)^2, tiny) ----
        double mrow = fabs(Sr[0]);
#pragma unroll
        for (int j2 = 1; j2 < 16; j2++) mrow = fmax(mrow, fabs(Sr[j2]));
        float mf = max16f((float)mrow);
        const double flo = 1e-12 * (double)mf;
        const double flo2 = fmax(flo * flo, 1e-280);

        // ---- rhs read: one register per lane; r<2 carries R, r>=2 carries I ----
        double ysol = Gst[r >> 1][q];

        // ---- 16x16 block-LDLT (2x2 diag blocks, identity-block unit L) +
        //      FUSED forward solve. 8 serial blocks, one drcp each. ----
        double m0 = 0.0, m1 = 0.0;   // D-solve coeffs: y = m0*w_self + m1*w_partner
#pragma unroll
        for (int p = 0; p < 8; p++) {
            const int k0 = 2 * p, k1 = 2 * p + 1;
            double W0 = Sr[k0], W1 = Sr[k1];       // raw columns (valid rows q>=k0)
            double av = rld(W0, k0);               // S[k0][k0]
            double bv = rld(W0, k1);               // S[k1][k0]
            double cv = rld(W1, k1);               // S[k1][k1]
            double det = fmax(av * cv - bv * bv, flo2);
            double idet = drcp(det);
            // L block-columns (rows q>k1): L = [W0 W1] * inv([[a,b],[b,c]])
            double L0 = (W0 * cv - W1 * bv) * idet;
            double L1 = (W1 * av - W0 * bv) * idet;
            if (l < 16) { Lst[k0 * 17 + l] = L0; Lst[k1 * 17 + l] = L1; }
            // D-solve coefficients (inv = idet*[[c,-b],[-b,a]])
            m0 = (q == k0) ? idet * cv : ((q == k1) ? idet * av : m0);
            m1 = (q == k0 || q == k1) ? -(idet * bv) : m1;
            // fused forward (identity diag block: w[k0],w[k1] already final)
            double t0a = rld(ysol, k0), t0b = rld(ysol, k0 + 32);
            double t1a = rld(ysol, k1), t1b = rld(ysol, k1 + 32);
            double w0 = (r < 2) ? t0a : t0b;
            double w1 = (r < 2) ? t1a : t1b;
            if (q > k1) ysol -= L0 * w0 + L1 * w1;
            // rank-2 update of the trailing columns
#pragma unroll
            for (int jj = k1 + 1; jj < 16; jj++)
                Sr[jj] -= L0 * rld(W0, jj) + L1 * rld(W1, jj);
        }

        // ---- block D-divide: partner value via DPP quad_perm [1,0,3,2] (l^1) ----
        double wpart = dppd<0xB1>(ysol);
        ysol = m0 * ysol + m1 * wpart;

        // ---- gather L^T row from LDS (issued before the bwd chain starts) ----
        double LTr[16];
#pragma unroll
        for (int kk = 0; kk < 16; kk++) LTr[kk] = Lst[q * 17 + kk];  // L[kk][q]

        // ---- backward solve L^T qc = v (block rank-2 steps, depth 8) ----
#pragma unroll
        for (int p = 7; p >= 0; p--) {
            const int k0 = 2 * p, k1 = 2 * p + 1;
            double t0a = rld(ysol, k0), t0b = rld(ysol, k0 + 32);
            double t1a = rld(ysol, k1), t1b = rld(ysol, k1 + 32);
            double y0 = (r < 2) ? t0a : t0b;
            double y1 = (r < 2) ? t1a : t1b;
            if (q < k0) ysol -= LTr[k0] * y0 + LTr[k1] * y1;
        }
        // lanes 0..15: ysol = qcR[q]; lanes 32..47: ysol = qcI[q]

        // ---- gather qc per own columns (sourced from the valid halves) ----
        double qc1c[4], qcvc[4];
#pragma unroll
        for (int c = 0; c < 4; c++) {
            qc1c[c] = __shfl(ysol, 4 * c + r, 64);
            qcvc[c] = __shfl(ysol, 32 + 4 * c + r, 64);
        }

        // ---- qr = ar*(g_r - sum_j C[q][j] qc_j) (cross4 reduction) ----
        double pr1 = iD[0]*qc1c[0] + iD[1]*qc1c[1] + iD[2]*qc1c[2] + iD[3]*qc1c[3];
        double prv = iD[0]*qcvc[0] + iD[1]*qcvc[1] + iD[2]*qcvc[2] + iD[3]*qcvc[3];
        double qr1 = ar * (rsR - cross4d(pr1));
        double qrv = ar * (rsI - cross4d(prv));

        // ---- u = H^{-1} r1, v = H^{-1} 1 ----
        double u[4], v[4];
#pragma unroll
        for (int c = 0; c < 4; c++) {
            u[c] = (r1[c] - qr1 - qc1c[c]) * iD[c];
            v[c] = (1.0  - qrv - qcvc[c]) * iD[c];
        }
        double urow = cross4d(u[0] + u[1] + u[2] + u[3]);
        double vrow = cross4d(v[0] + v[1] + v[2] + v[3]);
        double usum = sum16d(urow);
        double vsum = sum16d(vrow);
        double dy = (ra - usum) * drcp(vsum);

        // ---- dx + sums (rsdx reuses urow/vrow) ----
        double dx[4];
#pragma unroll
        for (int c = 0; c < 4; c++) dx[c] = -u[c] - v[c] * dy;
        double rsdx = -urow - vrow * dy;
        double csdx[4];
#pragma unroll
        for (int c = 0; c < 4; c++) csdx[c] = sum16d(dx[c]);
        double sumdx = -usum - vsum * dy;   // sum over all cells of dx (exact identity)

        // ---- ds, dz; SEPARATE primal/dual ratio tests (fp32, 0.99 margin) ----
        float amP = 1e30f, amD = 1e30f;
        double ds[4], dz[4];
#pragma unroll
        for (int c = 0; c < 4; c++) {
            ds[c] = dx[c] - rp[c];
            dz[c] = -(rs[c] + z[c] * ds[c]) * is_[c];
            if (ds[c] < 0.0) amP = fminf(amP, (float)s[c] * frcpf((float)(-ds[c])));
            if (dz[c] < 0.0) amD = fminf(amD, (float)z[c] * frcpf((float)(-dz[c])));
        }
        double ds_rt = -rp_rt - rsdx;
        double dz_rt = -(rs_rt + z_rt * ds_rt) * is_rt;
        if (ds_rt < 0.0) amP = fminf(amP, (float)s_rt * frcpf((float)(-ds_rt)));
        if (dz_rt < 0.0) amD = fminf(amD, (float)z_rt * frcpf((float)(-dz_rt)));
        double ds_ct[4], dz_ct[4];
#pragma unroll
        for (int c = 0; c < 4; c++) {
            ds_ct[c] = -rp_ct[c] - csdx[c];
            dz_ct[c] = -(rs_ct[c] + z_ct[c] * ds_ct[c]) * is_ct[c];
            if (ds_ct[c] < 0.0) amP = fminf(amP, (float)s_ct[c] * frcpf((float)(-ds_ct[c])));
            if (dz_ct[c] < 0.0) amD = fminf(amD, (float)z_ct[c] * frcpf((float)(-dz_ct[c])));
        }
        float aPf = min16f(cross4minf(amP));
        float aDf = min16f(cross4minf(amD));
        double alphaP = 0.99 * fmin(1.0, (double)aPf);
        double alphaD = 0.99 * fmin(1.0, (double)aDf);
        bool good = ((dy - dy) == 0.0);   // freeze on garbage direction
        alphaP = good ? alphaP : 0.0;
        alphaD = good ? alphaD : 0.0;

        // ---- step (x,s with alphaP; z,y with alphaD; x-sums incremental) ----
#pragma unroll
        for (int c = 0; c < 4; c++) {
            x[c] += alphaP * dx[c];
            s[c] += alphaP * ds[c];
            z[c] += alphaD * dz[c];
            s_ct[c] += alphaP * ds_ct[c];
            z_ct[c] += alphaD * dz_ct[c];
            cs[c] += alphaP * csdx[c];
        }
        yv += alphaD * dy;
        s_rt += alphaP * ds_rt;
        z_rt += alphaD * dz_rt;
        rsx += alphaP * rsdx;
        ra  += alphaP * sumdx;
    }

    // ---- emd = p.x + |sum w1 - sum w2| ----
    double e = sum16d(cross4d(px[0]*x[0] + px[1]*x[1] + px[2]*x[2] + px[3]*x[3]));
    if (l == 0) out[b] = (float)(e + sE);
}

extern "C" void kernel_launch(void* const* d_in, const int* in_sizes, int n_in,
                              void* d_out, int out_size, void* d_ws, size_t ws_size,
                              hipStream_t stream) {
    const float* jets1 = (const float*)d_in[0];
    const float* jets2 = (const float*)d_in[1];
    float* out = (float*)d_out;
    int B = in_sizes[0] / 48;   // 32
    emd_ip_kernel<<<dim3(B), dim3(64), 0, stream>>>(jets1, jets2, out);
}